// Round 19
// baseline (266.168 us; speedup 1.0000x reference)
//
#include <hip/hip_runtime.h>

#define B_SZ 16384
#define D_SZ 1024
#define H_SZ 2048
#define C_SZ 128
#define T_STEPS 20

typedef __attribute__((ext_vector_type(4))) float f32x4;
typedef __attribute__((ext_vector_type(4))) int   i32x4;

__device__ __forceinline__ signed char to_i8(float f, float s) {
    float v = rintf(s * f);
    v = v > 127.0f ? 127.0f : (v < -127.0f ? -127.0f : v);
    return (signed char)(int)v;
}

__device__ __forceinline__ void gl_lds16(const void* g, void* l) {
    __builtin_amdgcn_global_load_lds(
        (const __attribute__((address_space(1))) unsigned int*)g,
        (__attribute__((address_space(3))) unsigned int*)l, 16, 0, 0);
}

// ---------------- W1 -> i8 frags: [p(16)][kt(16)][wr(2)][m(4)][lane(64)][16B] --------
__global__ void k_w1fragi8(const float* __restrict__ W1, signed char* __restrict__ w1f) {
    int idx = blockIdx.x * blockDim.x + threadIdx.x;   // 0..131071
    int lane = idx & 63;
    int m    = (idx >> 6) & 3;
    int wr   = (idx >> 8) & 1;
    int kt   = (idx >> 9) & 15;
    int p    = idx >> 13;
    int h = p * 128 + wr * 64 + m * 16 + (lane & 15);
    int k = kt * 64 + (lane >> 4) * 16;
    const float* src = W1 + (size_t)h * D_SZ + k;
    union { signed char b[16]; uint4 u; } q;
    #pragma unroll
    for (int q4 = 0; q4 < 4; ++q4) {
        float4 v = *reinterpret_cast<const float4*>(src + q4 * 4);
        q.b[q4 * 4 + 0] = to_i8(v.x, 1024.0f);
        q.b[q4 * 4 + 1] = to_i8(v.y, 1024.0f);
        q.b[q4 * 4 + 2] = to_i8(v.z, 1024.0f);
        q.b[q4 * 4 + 3] = to_i8(v.w, 1024.0f);
    }
    size_t off = (size_t)p * 131072 + (size_t)kt * 8192 + wr * 4096 + m * 1024 + lane * 16;
    *reinterpret_cast<uint4*>(w1f + off) = q.u;
}

// ---------------- x -> i8 frags: [bp(128)][kt(16)][wc(2)][n(4)][lane(64)][16B] -------
__global__ void k_xfragi8(const float* __restrict__ x, signed char* __restrict__ xf) {
    int idx = blockIdx.x * blockDim.x + threadIdx.x;   // 0..1048575
    int lane = idx & 63;
    int n    = (idx >> 6) & 3;
    int wc   = (idx >> 8) & 1;
    int kt   = (idx >> 9) & 15;
    int bp   = idx >> 13;
    int b = bp * 128 + wc * 64 + n * 16 + (lane & 15);
    int k = kt * 64 + (lane >> 4) * 16;
    const float* src = x + (size_t)b * D_SZ + k;
    union { signed char b[16]; uint4 u; } q;
    #pragma unroll
    for (int q4 = 0; q4 < 4; ++q4) {
        float4 v = *reinterpret_cast<const float4*>(src + q4 * 4);
        q.b[q4 * 4 + 0] = to_i8(v.x, 32.0f);
        q.b[q4 * 4 + 1] = to_i8(v.y, 32.0f);
        q.b[q4 * 4 + 2] = to_i8(v.z, 32.0f);
        q.b[q4 * 4 + 3] = to_i8(v.w, 32.0f);
    }
    size_t off = (size_t)bp * 131072 + (size_t)kt * 8192 + wc * 4096 + n * 1024 + lane * 16;
    *reinterpret_cast<uint4*>(xf + off) = q.u;
}

// ---------------- W2 -> i8 frags: [kt64(32)][nt(8)][lane(64)][16B], k-perm baked -----
__global__ void k_w2fragi8(const float* __restrict__ W2, signed char* __restrict__ w2q) {
    const int perm4[4] = {0, 2, 1, 3};
    int idx = blockIdx.x * blockDim.x + threadIdx.x;   // 0..16383
    int lane = idx & 63;
    int nt   = (idx >> 6) & 7;
    int kt   = idx >> 9;                               // 0..31
    int c = nt * 16 + (lane & 15);
    int hbase = kt * 64 + (lane >> 4) * 16;
    const float* src = W2 + (size_t)c * H_SZ + hbase;
    float f[16];
    #pragma unroll
    for (int q4 = 0; q4 < 4; ++q4) {
        float4 v = *reinterpret_cast<const float4*>(src + q4 * 4);
        f[q4 * 4 + 0] = v.x; f[q4 * 4 + 1] = v.y; f[q4 * 4 + 2] = v.z; f[q4 * 4 + 3] = v.w;
    }
    union { signed char b[16]; uint4 u; } q;
    #pragma unroll
    for (int j = 0; j < 16; ++j) {
        int k = (j & ~3) + perm4[j & 3];
        q.b[j] = to_i8(f[k], 1024.0f);
    }
    *reinterpret_cast<uint4*>(w2q + (size_t)idx * 16) = q.u;
}

// ---------------- K1: LDS-staged i8 GEMM + closed-form LIF, 1-byte p-code masks ------
// (round-18 kernel, unchanged)
__global__ __launch_bounds__(256, 2) void k_gemm1_i8(
    const signed char* __restrict__ xf,
    const signed char* __restrict__ w1f,
    const float* __restrict__ b1,
    unsigned char* __restrict__ M5,
    unsigned int* __restrict__ spike_count)
{
    __shared__ unsigned lutm[22];
    __shared__ int sred[4];
    __shared__ __align__(16) char sbuf[2][16384];   // [buf][A 8KB | B 8KB]
    const int tid  = threadIdx.x;
    if (tid < 22) {
        unsigned m = 0;
        if (tid >= 1 && tid <= 20)
            for (int t = tid - 1; t < T_STEPS; t += tid) m |= 1u << t;
        lutm[tid] = m;
    }

    const int wv   = tid >> 6;
    const int lane = tid & 63;
    const int l15  = lane & 15;
    const int g    = lane >> 4;
    const int wr   = wv >> 1;
    const int wc   = wv & 1;

    const int wg    = blockIdx.x;
    const int xcd   = wg & 7;
    const int local = wg >> 3;
    const int sc    = local >> 4;
    const int sl    = local & 15;
    const int b_panel = xcd * 16 + (sc >> 2) * 4 + (sl >> 2);
    const int h_idx   = (sc & 3) * 4 + (sl & 3);

    const signed char* Asrc = w1f + (size_t)h_idx * 131072;
    const signed char* Bsrc = xf + (size_t)b_panel * 131072;

    #pragma unroll
    for (int c = 0; c < 4; ++c) {
        int o = c * 4096 + wv * 1024;
        const signed char* s = (o < 8192) ? (Asrc + o + lane * 16)
                                          : (Bsrc + (o - 8192) + lane * 16);
        gl_lds16(s, sbuf[0] + o);
    }

    i32x4 acc[4][4];
    #pragma unroll
    for (int i = 0; i < 4; ++i)
        #pragma unroll
        for (int j = 0; j < 4; ++j)
            acc[i][j] = (i32x4){0, 0, 0, 0};

    for (int kt = 0; kt < 16; ++kt) {
        __syncthreads();
        if (kt < 15) {
            #pragma unroll
            for (int c = 0; c < 4; ++c) {
                int o = c * 4096 + wv * 1024;
                const signed char* s = (o < 8192)
                    ? (Asrc + (size_t)(kt + 1) * 8192 + o + lane * 16)
                    : (Bsrc + (size_t)(kt + 1) * 8192 + (o - 8192) + lane * 16);
                gl_lds16(s, sbuf[(kt + 1) & 1] + o);
            }
        }
        const char* base = sbuf[kt & 1];
        i32x4 A[4], Bv[4];
        #pragma unroll
        for (int m = 0; m < 4; ++m)
            A[m] = *reinterpret_cast<const i32x4*>(base + wr * 4096 + m * 1024 + lane * 16);
        #pragma unroll
        for (int n = 0; n < 4; ++n)
            Bv[n] = *reinterpret_cast<const i32x4*>(base + 8192 + wc * 4096 + n * 1024 + lane * 16);
        #pragma unroll
        for (int m = 0; m < 4; ++m)
            #pragma unroll
            for (int n = 0; n < 4; ++n)
                acc[m][n] = __builtin_amdgcn_mfma_i32_16x16x64_i8(
                    A[m], Bv[n], acc[m][n], 0, 0, 0);
    }

    int spikes = 0;
    #pragma unroll
    for (int m = 0; m < 4; ++m) {
        const int h0l = h_idx * 128 + wr * 64 + m * 16 + g * 4;
        const int kt64 = h_idx * 2 + wr;
        const int k2lane = m * 16 + l15;
        float4 bias = *reinterpret_cast<const float4*>(b1 + h0l);
        float bj[4] = {bias.x, bias.y, bias.z, bias.w};
        #pragma unroll
        for (int n = 0; n < 4; ++n) {
            const int bt = b_panel * 8 + wc * 4 + n;
            unsigned pcode = 0;
            #pragma unroll
            for (int j = 0; j < 4; ++j) {
                float i1 = __fmul_rn((float)acc[m][n][j], 3.0517578125e-05f) + bj[j];
                float arg = fmaf(-0.1f, __builtin_amdgcn_rcpf(i1), 1.0f);
                float pf = ceilf(__log2f(arg) * -6.578813478960192f);
                int p = (int)pf;
                p = p < 1 ? 1 : (p > 21 ? 21 : p);
                int pe = (i1 >= 0.113843485f) ? p : 0;
                spikes += __popc(lutm[pe]);
                pcode |= (unsigned)pe << (8 * j);
            }
            const size_t rec = ((size_t)bt * 32 + kt64) * 64 + k2lane;
            *reinterpret_cast<unsigned int*>(M5 + rec * 16 + g * 4) = pcode;
        }
    }
    #pragma unroll
    for (int off = 32; off > 0; off >>= 1)
        spikes += __shfl_down(spikes, off);
    if (lane == 0) sred[wv] = spikes;
    __syncthreads();
    if (tid == 0)
        atomicAdd(spike_count, (unsigned int)(sred[0] + sred[1] + sred[2] + sred[3]));
}

// ---------------- K2: layer 2 i8 K=64; pair-LUT emits A-operand bytes directly -------
// lut4[p0*22+p2][t] = u16{spike(p0,t), spike(p2,t)} (484 x 20, stride 22 u16).
// Per kt: 8 pair-pointers, then A[tl].u[g2] = lpA[tl] | lpB[tl]<<16 — 2 ds_read_u16
// + 2 VALU per A-u32. Replaces mask-LUT + repack + per-t bit extraction (~210 -> ~100
// VALU/kt); uniform for all t (tg3/w4/perm path gone). Bit-exact vs round 18.
__global__ __launch_bounds__(256, 2) void k_layer2_i8(
    const unsigned char* __restrict__ M5,
    const signed char* __restrict__ W2q,
    const float* __restrict__ b2,
    float* __restrict__ out)
{
    __shared__ __align__(16) char smem[39728];   // [0,18432) stage dbuf; [18432,39728) lut4; epi unions base
    float* sm_f32 = (float*)smem;
    unsigned short* lut4 = (unsigned short*)(smem + 18432);

    const int tid  = threadIdx.x;
    const int wv   = tid >> 6;
    const int tg   = wv;              // wave = t-group: t in [tg*5, tg*5+5)
    const int lane = tid & 63;
    const int l15  = lane & 15;
    const int g    = lane >> 4;
    const int b0   = blockIdx.x * 16;
    const int t0   = tg * 5;

    // init pair-LUT: lut4[pp*22 + t], pp = p0*22+p2
    for (int e = tid; e < 9680; e += 256) {
        int pp = e / 20;
        int t  = e - pp * 20;
        int p0 = pp / 22, p2 = pp - p0 * 22;
        unsigned c0 = (p0 >= 1 && ((t + 1) % p0) == 0) ? 1u : 0u;
        unsigned c1 = (p2 >= 1 && ((t + 1) % p2) == 0) ? 1u : 0u;
        lut4[pp * 22 + t] = (unsigned short)(c0 | (c1 << 8));
    }

    const size_t m5blk = (size_t)blockIdx.x * 32768;   // bytes

    i32x4 acc[8][5];
    #pragma unroll
    for (int n = 0; n < 8; ++n)
        #pragma unroll
        for (int t = 0; t < 5; ++t)
            acc[n][t] = (i32x4){0, 0, 0, 0};

    // prologue: stage kt=0 into buf 0. 9 chunks of 1KB: [0..7]=w2, [8]=pcodes
    for (int c = wv; c < 9; c += 4) {
        const char* s = (c < 8) ? ((const char*)W2q + c * 1024)
                                : ((const char*)M5 + m5blk);
        gl_lds16(s + lane * 16, smem + c * 1024);
    }

    const unsigned short* lutT = lut4 + t0;

    for (int kt = 0; kt < 32; ++kt) {
        __syncthreads();
        const int cb = (kt & 1) * 9216;
        if (kt < 31) {
            const int nb = ((kt + 1) & 1) * 9216;
            for (int c = wv; c < 9; c += 4) {
                const char* s = (c < 8)
                    ? ((const char*)W2q + (size_t)(kt + 1) * 8192 + c * 1024)
                    : ((const char*)M5 + m5blk + (size_t)(kt + 1) * 1024);
                gl_lds16(s + lane * 16, smem + nb + c * 1024);
            }
        }

        union { uint4 v; unsigned u[4]; } pc;
        pc.v = *reinterpret_cast<const uint4*>(smem + cb + 8192 + lane * 16);

        // pair pointers: bytes (j0,j2) and (j1,j3) of each pc word
        const unsigned short* lp[8];
        #pragma unroll
        for (int g2 = 0; g2 < 4; ++g2) {
            unsigned w = pc.u[g2];
            unsigned ppA = (w & 0xffu) * 22u + ((w >> 16) & 0xffu);
            unsigned ppB = ((w >> 8) & 0xffu) * 22u + (w >> 24);
            lp[2 * g2]     = lutT + ppA * 22u;
            lp[2 * g2 + 1] = lutT + ppB * 22u;
        }

        union { i32x4 v; unsigned u[4]; } A[5];
        #pragma unroll
        for (int tl = 0; tl < 5; ++tl)
            #pragma unroll
            for (int g2 = 0; g2 < 4; ++g2)
                A[tl].u[g2] = (unsigned)lp[2 * g2][tl] | ((unsigned)lp[2 * g2 + 1][tl] << 16);

        i32x4 Bv[8];
        #pragma unroll
        for (int nt = 0; nt < 8; ++nt)
            Bv[nt] = *reinterpret_cast<const i32x4*>(smem + cb + nt * 1024 + lane * 16);
        #pragma unroll
        for (int tl = 0; tl < 5; ++tl)
            #pragma unroll
            for (int nt = 0; nt < 8; ++nt)
                acc[nt][tl] = __builtin_amdgcn_mfma_i32_16x16x64_i8(
                    A[tl].v, Bv[nt], acc[nt][tl], 0, 0, 0);
    }

    // epilogue: 8 chunks of 16 cols; transpose through LDS, then LIF per (b,c)
    #pragma unroll
    for (int q = 0; q < 8; ++q) {
        __syncthreads();
        #pragma unroll
        for (int tl = 0; tl < 5; ++tl)
            #pragma unroll
            for (int j = 0; j < 4; ++j)
                sm_f32[((g * 4 + j) * 17 + l15) * 21 + (t0 + tl)] = (float)acc[q][tl][j];
        __syncthreads();
        {
            const int bl  = tid >> 4;     // 0..15
            const int c16 = tid & 15;
            const int c   = q * 16 + c16;
            const float bias = b2[c];
            float u2 = 0.0f; int cnt = 0;
            #pragma unroll
            for (int t = 0; t < T_STEPS; ++t) {
                float X = __fadd_rn(__fmul_rn(sm_f32[(bl * 17 + c16) * 21 + t], 0.0009765625f), bias);
                u2 = __fadd_rn(__fmul_rn(0.9f, u2), X);
                if (u2 >= 1.0f) { cnt++; u2 = 0.0f; }
            }
            out[(size_t)(b0 + bl) * C_SZ + c] = (float)cnt / 20.0f;
        }
    }
}

// ---------------- K3: mean_spikes = total / (B * T) ----------------
__global__ void k_finalize(const unsigned int* __restrict__ spike_count, float* __restrict__ out) {
    out[(size_t)B_SZ * C_SZ] = (float)(*spike_count) / (float)((size_t)B_SZ * T_STEPS);
}

extern "C" void kernel_launch(void* const* d_in, const int* in_sizes, int n_in,
                              void* d_out, int out_size, void* d_ws, size_t ws_size,
                              hipStream_t stream) {
    const float* x  = (const float*)d_in[0];
    const float* W1 = (const float*)d_in[1];
    const float* b1 = (const float*)d_in[2];
    const float* W2 = (const float*)d_in[3];
    const float* b2 = (const float*)d_in[4];
    float* out = (float*)d_out;

    char* ws = (char*)d_ws;
    const size_t m5_b   = (size_t)B_SZ * H_SZ;       // 33.6 MB
    const size_t xfi_b  = (size_t)B_SZ * D_SZ;       // 16.8 MB
    const size_t w1fi_b = (size_t)H_SZ * D_SZ;       //  2.1 MB
    const size_t w2q_b  = (size_t)C_SZ * H_SZ;       //  0.26 MB

    size_t off = 0;
    unsigned char*  M5   = (unsigned char*)(ws + off);  off += m5_b;
    signed char*    xfi  = (signed char*)(ws + off);    off += xfi_b;
    signed char*    w1fi = (signed char*)(ws + off);    off += w1fi_b;
    signed char*    w2q  = (signed char*)(ws + off);    off += w2q_b;
    unsigned int* counter = (unsigned int*)(ws + off);  off += 256;

    hipMemsetAsync(counter, 0, sizeof(unsigned int), stream);

    k_w1fragi8<<<512, 256, 0, stream>>>(W1, w1fi);   // 131072 threads EXACT
    k_w2fragi8<<<64, 256, 0, stream>>>(W2, w2q);     // 16384 threads EXACT
    k_xfragi8<<<4096, 256, 0, stream>>>(x, xfi);     // 1048576 threads EXACT

    k_gemm1_i8<<<2048, 256, 0, stream>>>(xfi, w1fi, b1, M5, counter);

    k_layer2_i8<<<B_SZ / 16, 256, 0, stream>>>(M5, w2q, b2, out);

    k_finalize<<<1, 1, 0, stream>>>(counter, out);
}

// Round 20
// 249.196 us; speedup vs baseline: 1.0681x; 1.0681x over previous
//
#include <hip/hip_runtime.h>

#define B_SZ 16384
#define D_SZ 1024
#define H_SZ 2048
#define C_SZ 128
#define T_STEPS 20

typedef __attribute__((ext_vector_type(4))) float f32x4;
typedef __attribute__((ext_vector_type(4))) int   i32x4;

__device__ __forceinline__ signed char to_i8(float f, float s) {
    float v = rintf(s * f);
    v = v > 127.0f ? 127.0f : (v < -127.0f ? -127.0f : v);
    return (signed char)(int)v;
}

__device__ __forceinline__ void gl_lds16(const void* g, void* l) {
    __builtin_amdgcn_global_load_lds(
        (const __attribute__((address_space(1))) unsigned int*)g,
        (__attribute__((address_space(3))) unsigned int*)l, 16, 0, 0);
}

// ---------------- W1 -> i8 frags: [p(16)][kt(16)][wr(2)][m(4)][lane(64)][16B] --------
__global__ void k_w1fragi8(const float* __restrict__ W1, signed char* __restrict__ w1f) {
    int idx = blockIdx.x * blockDim.x + threadIdx.x;   // 0..131071
    int lane = idx & 63;
    int m    = (idx >> 6) & 3;
    int wr   = (idx >> 8) & 1;
    int kt   = (idx >> 9) & 15;
    int p    = idx >> 13;
    int h = p * 128 + wr * 64 + m * 16 + (lane & 15);
    int k = kt * 64 + (lane >> 4) * 16;
    const float* src = W1 + (size_t)h * D_SZ + k;
    union { signed char b[16]; uint4 u; } q;
    #pragma unroll
    for (int q4 = 0; q4 < 4; ++q4) {
        float4 v = *reinterpret_cast<const float4*>(src + q4 * 4);
        q.b[q4 * 4 + 0] = to_i8(v.x, 1024.0f);
        q.b[q4 * 4 + 1] = to_i8(v.y, 1024.0f);
        q.b[q4 * 4 + 2] = to_i8(v.z, 1024.0f);
        q.b[q4 * 4 + 3] = to_i8(v.w, 1024.0f);
    }
    size_t off = (size_t)p * 131072 + (size_t)kt * 8192 + wr * 4096 + m * 1024 + lane * 16;
    *reinterpret_cast<uint4*>(w1f + off) = q.u;
}

// ---------------- x -> i8 frags: [bp(128)][kt(16)][wc(2)][n(4)][lane(64)][16B] -------
__global__ void k_xfragi8(const float* __restrict__ x, signed char* __restrict__ xf) {
    int idx = blockIdx.x * blockDim.x + threadIdx.x;   // 0..1048575
    int lane = idx & 63;
    int n    = (idx >> 6) & 3;
    int wc   = (idx >> 8) & 1;
    int kt   = (idx >> 9) & 15;
    int bp   = idx >> 13;
    int b = bp * 128 + wc * 64 + n * 16 + (lane & 15);
    int k = kt * 64 + (lane >> 4) * 16;
    const float* src = x + (size_t)b * D_SZ + k;
    union { signed char b[16]; uint4 u; } q;
    #pragma unroll
    for (int q4 = 0; q4 < 4; ++q4) {
        float4 v = *reinterpret_cast<const float4*>(src + q4 * 4);
        q.b[q4 * 4 + 0] = to_i8(v.x, 32.0f);
        q.b[q4 * 4 + 1] = to_i8(v.y, 32.0f);
        q.b[q4 * 4 + 2] = to_i8(v.z, 32.0f);
        q.b[q4 * 4 + 3] = to_i8(v.w, 32.0f);
    }
    size_t off = (size_t)bp * 131072 + (size_t)kt * 8192 + wc * 4096 + n * 1024 + lane * 16;
    *reinterpret_cast<uint4*>(xf + off) = q.u;
}

// ---------------- W2 -> i8 frags: [kt64(32)][nt(8)][lane(64)][16B], k-perm baked -----
__global__ void k_w2fragi8(const float* __restrict__ W2, signed char* __restrict__ w2q) {
    const int perm4[4] = {0, 2, 1, 3};
    int idx = blockIdx.x * blockDim.x + threadIdx.x;   // 0..16383
    int lane = idx & 63;
    int nt   = (idx >> 6) & 7;
    int kt   = idx >> 9;                               // 0..31
    int c = nt * 16 + (lane & 15);
    int hbase = kt * 64 + (lane >> 4) * 16;
    const float* src = W2 + (size_t)c * H_SZ + hbase;
    float f[16];
    #pragma unroll
    for (int q4 = 0; q4 < 4; ++q4) {
        float4 v = *reinterpret_cast<const float4*>(src + q4 * 4);
        f[q4 * 4 + 0] = v.x; f[q4 * 4 + 1] = v.y; f[q4 * 4 + 2] = v.z; f[q4 * 4 + 3] = v.w;
    }
    union { signed char b[16]; uint4 u; } q;
    #pragma unroll
    for (int j = 0; j < 16; ++j) {
        int k = (j & ~3) + perm4[j & 3];
        q.b[j] = to_i8(f[k], 1024.0f);
    }
    *reinterpret_cast<uint4*>(w2q + (size_t)idx * 16) = q.u;
}

// ---------------- K1: LDS-staged i8 GEMM + closed-form LIF, 1-byte p-code masks ------
// (round-18 kernel, unchanged)
__global__ __launch_bounds__(256, 2) void k_gemm1_i8(
    const signed char* __restrict__ xf,
    const signed char* __restrict__ w1f,
    const float* __restrict__ b1,
    unsigned char* __restrict__ M5,
    unsigned int* __restrict__ spike_count)
{
    __shared__ unsigned lutm[22];
    __shared__ int sred[4];
    __shared__ __align__(16) char sbuf[2][16384];   // [buf][A 8KB | B 8KB]
    const int tid  = threadIdx.x;
    if (tid < 22) {
        unsigned m = 0;
        if (tid >= 1 && tid <= 20)
            for (int t = tid - 1; t < T_STEPS; t += tid) m |= 1u << t;
        lutm[tid] = m;
    }

    const int wv   = tid >> 6;
    const int lane = tid & 63;
    const int l15  = lane & 15;
    const int g    = lane >> 4;
    const int wr   = wv >> 1;
    const int wc   = wv & 1;

    const int wg    = blockIdx.x;
    const int xcd   = wg & 7;
    const int local = wg >> 3;
    const int sc    = local >> 4;
    const int sl    = local & 15;
    const int b_panel = xcd * 16 + (sc >> 2) * 4 + (sl >> 2);
    const int h_idx   = (sc & 3) * 4 + (sl & 3);

    const signed char* Asrc = w1f + (size_t)h_idx * 131072;
    const signed char* Bsrc = xf + (size_t)b_panel * 131072;

    #pragma unroll
    for (int c = 0; c < 4; ++c) {
        int o = c * 4096 + wv * 1024;
        const signed char* s = (o < 8192) ? (Asrc + o + lane * 16)
                                          : (Bsrc + (o - 8192) + lane * 16);
        gl_lds16(s, sbuf[0] + o);
    }

    i32x4 acc[4][4];
    #pragma unroll
    for (int i = 0; i < 4; ++i)
        #pragma unroll
        for (int j = 0; j < 4; ++j)
            acc[i][j] = (i32x4){0, 0, 0, 0};

    for (int kt = 0; kt < 16; ++kt) {
        __syncthreads();
        if (kt < 15) {
            #pragma unroll
            for (int c = 0; c < 4; ++c) {
                int o = c * 4096 + wv * 1024;
                const signed char* s = (o < 8192)
                    ? (Asrc + (size_t)(kt + 1) * 8192 + o + lane * 16)
                    : (Bsrc + (size_t)(kt + 1) * 8192 + (o - 8192) + lane * 16);
                gl_lds16(s, sbuf[(kt + 1) & 1] + o);
            }
        }
        const char* base = sbuf[kt & 1];
        i32x4 A[4], Bv[4];
        #pragma unroll
        for (int m = 0; m < 4; ++m)
            A[m] = *reinterpret_cast<const i32x4*>(base + wr * 4096 + m * 1024 + lane * 16);
        #pragma unroll
        for (int n = 0; n < 4; ++n)
            Bv[n] = *reinterpret_cast<const i32x4*>(base + 8192 + wc * 4096 + n * 1024 + lane * 16);
        #pragma unroll
        for (int m = 0; m < 4; ++m)
            #pragma unroll
            for (int n = 0; n < 4; ++n)
                acc[m][n] = __builtin_amdgcn_mfma_i32_16x16x64_i8(
                    A[m], Bv[n], acc[m][n], 0, 0, 0);
    }

    int spikes = 0;
    #pragma unroll
    for (int m = 0; m < 4; ++m) {
        const int h0l = h_idx * 128 + wr * 64 + m * 16 + g * 4;
        const int kt64 = h_idx * 2 + wr;
        const int k2lane = m * 16 + l15;
        float4 bias = *reinterpret_cast<const float4*>(b1 + h0l);
        float bj[4] = {bias.x, bias.y, bias.z, bias.w};
        #pragma unroll
        for (int n = 0; n < 4; ++n) {
            const int bt = b_panel * 8 + wc * 4 + n;
            unsigned pcode = 0;
            #pragma unroll
            for (int j = 0; j < 4; ++j) {
                float i1 = __fmul_rn((float)acc[m][n][j], 3.0517578125e-05f) + bj[j];
                float arg = fmaf(-0.1f, __builtin_amdgcn_rcpf(i1), 1.0f);
                float pf = ceilf(__log2f(arg) * -6.578813478960192f);
                int p = (int)pf;
                p = p < 1 ? 1 : (p > 21 ? 21 : p);
                int pe = (i1 >= 0.113843485f) ? p : 0;
                spikes += __popc(lutm[pe]);
                pcode |= (unsigned)pe << (8 * j);
            }
            const size_t rec = ((size_t)bt * 32 + kt64) * 64 + k2lane;
            *reinterpret_cast<unsigned int*>(M5 + rec * 16 + g * 4) = pcode;
        }
    }
    #pragma unroll
    for (int off = 32; off > 0; off >>= 1)
        spikes += __shfl_down(spikes, off);
    if (lane == 0) sred[wv] = spikes;
    __syncthreads();
    if (tid == 0)
        atomicAdd(spike_count, (unsigned int)(sred[0] + sred[1] + sred[2] + sred[3]));
}

// ---------------- K2: layer 2 i8 K=64; spread-LUT + v_perm A-build -------------------
// 320 thr = 5 waves; wave tg owns 4 timesteps (t = 4tg..4tg+3) x 128 cols, 16 b/block.
// lut5[tg][p][replica 32] = 4 pre-spread spike bytes for (p, t=4tg+0..3); addr =
// (p<<5)|lane&31 -> always own bank (round-19 lesson: data-dep LDS needs replication).
// Per element: 1 conflict-free ds_read_b32; 8 v_perm per quad transpose to A words.
// Bit-exact vs round 18.
__global__ __launch_bounds__(320, 2) void k_layer2_i8(
    const unsigned char* __restrict__ M5,
    const signed char* __restrict__ W2q,
    const float* __restrict__ b2,
    float* __restrict__ out)
{
    __shared__ __align__(16) char smem[32512];   // [0,18432) stage dbuf; [18432,32512) lut5; epi overlaps
    float* sm_f32 = (float*)smem;
    unsigned* lut5 = (unsigned*)(smem + 18432);  // [tg(5)][p(22)][32]

    const int tid  = threadIdx.x;
    const int wv   = tid >> 6;        // 0..4
    const int tg   = wv;              // t in [tg*4, tg*4+4)
    const int lane = tid & 63;
    const int l15  = lane & 15;
    const int g    = lane >> 4;
    const int b0   = blockIdx.x * 16;
    const int t0   = tg * 4;
    const int lsl  = lane & 31;

    // init lut5: entry = spread bytes {spike(p, 4tgi+tl)}_{tl=0..3}, replicated x32
    for (int e = tid; e < 3520; e += 320) {
        int tgi = e / 704;
        int rem = e - tgi * 704;
        int p   = rem >> 5;
        unsigned v = 0;
        #pragma unroll
        for (int tl = 0; tl < 4; ++tl) {
            int t = tgi * 4 + tl;
            unsigned c = (p >= 1 && ((t + 1) % p) == 0) ? 1u : 0u;
            v |= c << (8 * tl);
        }
        lut5[e] = v;
    }

    const size_t m5blk = (size_t)blockIdx.x * 32768;   // bytes

    i32x4 acc[8][4];
    #pragma unroll
    for (int n = 0; n < 8; ++n)
        #pragma unroll
        for (int t = 0; t < 4; ++t)
            acc[n][t] = (i32x4){0, 0, 0, 0};

    // prologue: stage kt=0 into buf 0. 9 chunks of 1KB: [0..7]=w2, [8]=pcodes
    for (int c = wv; c < 9; c += 5) {
        const char* s = (c < 8) ? ((const char*)W2q + c * 1024)
                                : ((const char*)M5 + m5blk);
        gl_lds16(s + lane * 16, smem + c * 1024);
    }

    const unsigned* lutT = lut5 + tg * 704 + lsl;

    for (int kt = 0; kt < 32; ++kt) {
        __syncthreads();
        const int cb = (kt & 1) * 9216;
        if (kt < 31) {
            const int nb = ((kt + 1) & 1) * 9216;
            for (int c = wv; c < 9; c += 5) {
                const char* s = (c < 8)
                    ? ((const char*)W2q + (size_t)(kt + 1) * 8192 + c * 1024)
                    : ((const char*)M5 + m5blk + (size_t)(kt + 1) * 1024);
                gl_lds16(s + lane * 16, smem + nb + c * 1024);
            }
        }

        union { uint4 v; unsigned u[4]; } pc;
        pc.v = *reinterpret_cast<const uint4*>(smem + cb + 8192 + lane * 16);

        union { i32x4 v; unsigned u[4]; } A[4];
        #pragma unroll
        for (int g2 = 0; g2 < 4; ++g2) {
            unsigned w = pc.u[g2];
            unsigned q0 = lutT[((w      ) & 0xffu) << 5];
            unsigned q1 = lutT[((w >>  8) & 0xffu) << 5];
            unsigned q2 = lutT[((w >> 16) & 0xffu) << 5];
            unsigned q3 = lutT[( w >> 24         ) << 5];
            // 4x4 byte transpose; A word byte order {j0, j2, j1, j3} matches w2q perm
            unsigned u01 = __builtin_amdgcn_perm(q2, q0, 0x05010400u); // [q0.0,q2.0,q0.1,q2.1]
            unsigned u23 = __builtin_amdgcn_perm(q3, q1, 0x05010400u);
            unsigned v01 = __builtin_amdgcn_perm(q2, q0, 0x07030602u); // [q0.2,q2.2,q0.3,q2.3]
            unsigned v23 = __builtin_amdgcn_perm(q3, q1, 0x07030602u);
            A[0].u[g2] = __builtin_amdgcn_perm(u23, u01, 0x05040100u);
            A[1].u[g2] = __builtin_amdgcn_perm(u23, u01, 0x07060302u);
            A[2].u[g2] = __builtin_amdgcn_perm(v23, v01, 0x05040100u);
            A[3].u[g2] = __builtin_amdgcn_perm(v23, v01, 0x07060302u);
        }

        i32x4 Bv[8];
        #pragma unroll
        for (int nt = 0; nt < 8; ++nt)
            Bv[nt] = *reinterpret_cast<const i32x4*>(smem + cb + nt * 1024 + lane * 16);
        #pragma unroll
        for (int tl = 0; tl < 4; ++tl)
            #pragma unroll
            for (int nt = 0; nt < 8; ++nt)
                acc[nt][tl] = __builtin_amdgcn_mfma_i32_16x16x64_i8(
                    A[tl].v, Bv[nt], acc[nt][tl], 0, 0, 0);
    }

    // epilogue: 8 chunks of 16 cols; transpose through LDS, then LIF per (b,c)
    #pragma unroll
    for (int q = 0; q < 8; ++q) {
        __syncthreads();
        #pragma unroll
        for (int tl = 0; tl < 4; ++tl)
            #pragma unroll
            for (int j = 0; j < 4; ++j)
                sm_f32[((g * 4 + j) * 17 + l15) * 21 + (t0 + tl)] = (float)acc[q][tl][j];
        __syncthreads();
        if (tid < 256) {
            const int bl  = tid >> 4;     // 0..15
            const int c16 = tid & 15;
            const int c   = q * 16 + c16;
            const float bias = b2[c];
            float u2 = 0.0f; int cnt = 0;
            #pragma unroll
            for (int t = 0; t < T_STEPS; ++t) {
                float X = __fadd_rn(__fmul_rn(sm_f32[(bl * 17 + c16) * 21 + t], 0.0009765625f), bias);
                u2 = __fadd_rn(__fmul_rn(0.9f, u2), X);
                if (u2 >= 1.0f) { cnt++; u2 = 0.0f; }
            }
            out[(size_t)(b0 + bl) * C_SZ + c] = (float)cnt / 20.0f;
        }
    }
}

// ---------------- K3: mean_spikes = total / (B * T) ----------------
__global__ void k_finalize(const unsigned int* __restrict__ spike_count, float* __restrict__ out) {
    out[(size_t)B_SZ * C_SZ] = (float)(*spike_count) / (float)((size_t)B_SZ * T_STEPS);
}

extern "C" void kernel_launch(void* const* d_in, const int* in_sizes, int n_in,
                              void* d_out, int out_size, void* d_ws, size_t ws_size,
                              hipStream_t stream) {
    const float* x  = (const float*)d_in[0];
    const float* W1 = (const float*)d_in[1];
    const float* b1 = (const float*)d_in[2];
    const float* W2 = (const float*)d_in[3];
    const float* b2 = (const float*)d_in[4];
    float* out = (float*)d_out;

    char* ws = (char*)d_ws;
    const size_t m5_b   = (size_t)B_SZ * H_SZ;       // 33.6 MB
    const size_t xfi_b  = (size_t)B_SZ * D_SZ;       // 16.8 MB
    const size_t w1fi_b = (size_t)H_SZ * D_SZ;       //  2.1 MB
    const size_t w2q_b  = (size_t)C_SZ * H_SZ;       //  0.26 MB

    size_t off = 0;
    unsigned char*  M5   = (unsigned char*)(ws + off);  off += m5_b;
    signed char*    xfi  = (signed char*)(ws + off);    off += xfi_b;
    signed char*    w1fi = (signed char*)(ws + off);    off += w1fi_b;
    signed char*    w2q  = (signed char*)(ws + off);    off += w2q_b;
    unsigned int* counter = (unsigned int*)(ws + off);  off += 256;

    hipMemsetAsync(counter, 0, sizeof(unsigned int), stream);

    k_w1fragi8<<<512, 256, 0, stream>>>(W1, w1fi);   // 131072 threads EXACT
    k_w2fragi8<<<64, 256, 0, stream>>>(W2, w2q);     // 16384 threads EXACT
    k_xfragi8<<<4096, 256, 0, stream>>>(x, xfi);     // 1048576 threads EXACT

    k_gemm1_i8<<<2048, 256, 0, stream>>>(xfi, w1fi, b1, M5, counter);

    k_layer2_i8<<<B_SZ / 16, 320, 0, stream>>>(M5, w2q, b2, out);

    k_finalize<<<1, 1, 0, stream>>>(counter, out);
}

// Round 21
// 187.922 us; speedup vs baseline: 1.4164x; 1.3261x over previous
//
#include <hip/hip_runtime.h>

#define B_SZ 16384
#define D_SZ 1024
#define H_SZ 2048
#define C_SZ 128
#define T_STEPS 20

typedef __attribute__((ext_vector_type(4))) float f32x4;
typedef __attribute__((ext_vector_type(4))) int   i32x4;

__device__ __forceinline__ signed char to_i8(float f, float s) {
    float v = rintf(s * f);
    v = v > 127.0f ? 127.0f : (v < -127.0f ? -127.0f : v);
    return (signed char)(int)v;
}

__device__ __forceinline__ void gl_lds16(const void* g, void* l) {
    __builtin_amdgcn_global_load_lds(
        (const __attribute__((address_space(1))) unsigned int*)g,
        (__attribute__((address_space(3))) unsigned int*)l, 16, 0, 0);
}

// ---------------- W1 -> i8 frags: [p(16)][kt(16)][wr(2)][m(4)][lane(64)][16B] --------
__global__ void k_w1fragi8(const float* __restrict__ W1, signed char* __restrict__ w1f) {
    int idx = blockIdx.x * blockDim.x + threadIdx.x;   // 0..131071
    int lane = idx & 63;
    int m    = (idx >> 6) & 3;
    int wr   = (idx >> 8) & 1;
    int kt   = (idx >> 9) & 15;
    int p    = idx >> 13;
    int h = p * 128 + wr * 64 + m * 16 + (lane & 15);
    int k = kt * 64 + (lane >> 4) * 16;
    const float* src = W1 + (size_t)h * D_SZ + k;
    union { signed char b[16]; uint4 u; } q;
    #pragma unroll
    for (int q4 = 0; q4 < 4; ++q4) {
        float4 v = *reinterpret_cast<const float4*>(src + q4 * 4);
        q.b[q4 * 4 + 0] = to_i8(v.x, 1024.0f);
        q.b[q4 * 4 + 1] = to_i8(v.y, 1024.0f);
        q.b[q4 * 4 + 2] = to_i8(v.z, 1024.0f);
        q.b[q4 * 4 + 3] = to_i8(v.w, 1024.0f);
    }
    size_t off = (size_t)p * 131072 + (size_t)kt * 8192 + wr * 4096 + m * 1024 + lane * 16;
    *reinterpret_cast<uint4*>(w1f + off) = q.u;
}

// ---------------- x -> i8 frags: [bp(128)][kt(16)][wc(2)][n(4)][lane(64)][16B] -------
__global__ void k_xfragi8(const float* __restrict__ x, signed char* __restrict__ xf) {
    int idx = blockIdx.x * blockDim.x + threadIdx.x;   // 0..1048575
    int lane = idx & 63;
    int n    = (idx >> 6) & 3;
    int wc   = (idx >> 8) & 1;
    int kt   = (idx >> 9) & 15;
    int bp   = idx >> 13;
    int b = bp * 128 + wc * 64 + n * 16 + (lane & 15);
    int k = kt * 64 + (lane >> 4) * 16;
    const float* src = x + (size_t)b * D_SZ + k;
    union { signed char b[16]; uint4 u; } q;
    #pragma unroll
    for (int q4 = 0; q4 < 4; ++q4) {
        float4 v = *reinterpret_cast<const float4*>(src + q4 * 4);
        q.b[q4 * 4 + 0] = to_i8(v.x, 32.0f);
        q.b[q4 * 4 + 1] = to_i8(v.y, 32.0f);
        q.b[q4 * 4 + 2] = to_i8(v.z, 32.0f);
        q.b[q4 * 4 + 3] = to_i8(v.w, 32.0f);
    }
    size_t off = (size_t)bp * 131072 + (size_t)kt * 8192 + wc * 4096 + n * 1024 + lane * 16;
    *reinterpret_cast<uint4*>(xf + off) = q.u;
}

// ---------------- W2 -> i8 frags: [kt64(32)][nt(8)][lane(64)][16B], k-perm baked -----
__global__ void k_w2fragi8(const float* __restrict__ W2, signed char* __restrict__ w2q) {
    const int perm4[4] = {0, 2, 1, 3};
    int idx = blockIdx.x * blockDim.x + threadIdx.x;   // 0..16383
    int lane = idx & 63;
    int nt   = (idx >> 6) & 7;
    int kt   = idx >> 9;                               // 0..31
    int c = nt * 16 + (lane & 15);
    int hbase = kt * 64 + (lane >> 4) * 16;
    const float* src = W2 + (size_t)c * H_SZ + hbase;
    float f[16];
    #pragma unroll
    for (int q4 = 0; q4 < 4; ++q4) {
        float4 v = *reinterpret_cast<const float4*>(src + q4 * 4);
        f[q4 * 4 + 0] = v.x; f[q4 * 4 + 1] = v.y; f[q4 * 4 + 2] = v.z; f[q4 * 4 + 3] = v.w;
    }
    union { signed char b[16]; uint4 u; } q;
    #pragma unroll
    for (int j = 0; j < 16; ++j) {
        int k = (j & ~3) + perm4[j & 3];
        q.b[j] = to_i8(f[k], 1024.0f);
    }
    *reinterpret_cast<uint4*>(w2q + (size_t)idx * 16) = q.u;
}

// ---------------- K1: LDS-staged i8 GEMM + closed-form LIF, 1-byte p-code masks ------
// (round-18 kernel, unchanged)
__global__ __launch_bounds__(256, 2) void k_gemm1_i8(
    const signed char* __restrict__ xf,
    const signed char* __restrict__ w1f,
    const float* __restrict__ b1,
    unsigned char* __restrict__ M5,
    unsigned int* __restrict__ spike_count)
{
    __shared__ unsigned lutm[22];
    __shared__ int sred[4];
    __shared__ __align__(16) char sbuf[2][16384];   // [buf][A 8KB | B 8KB]
    const int tid  = threadIdx.x;
    if (tid < 22) {
        unsigned m = 0;
        if (tid >= 1 && tid <= 20)
            for (int t = tid - 1; t < T_STEPS; t += tid) m |= 1u << t;
        lutm[tid] = m;
    }

    const int wv   = tid >> 6;
    const int lane = tid & 63;
    const int l15  = lane & 15;
    const int g    = lane >> 4;
    const int wr   = wv >> 1;
    const int wc   = wv & 1;

    const int wg    = blockIdx.x;
    const int xcd   = wg & 7;
    const int local = wg >> 3;
    const int sc    = local >> 4;
    const int sl    = local & 15;
    const int b_panel = xcd * 16 + (sc >> 2) * 4 + (sl >> 2);
    const int h_idx   = (sc & 3) * 4 + (sl & 3);

    const signed char* Asrc = w1f + (size_t)h_idx * 131072;
    const signed char* Bsrc = xf + (size_t)b_panel * 131072;

    #pragma unroll
    for (int c = 0; c < 4; ++c) {
        int o = c * 4096 + wv * 1024;
        const signed char* s = (o < 8192) ? (Asrc + o + lane * 16)
                                          : (Bsrc + (o - 8192) + lane * 16);
        gl_lds16(s, sbuf[0] + o);
    }

    i32x4 acc[4][4];
    #pragma unroll
    for (int i = 0; i < 4; ++i)
        #pragma unroll
        for (int j = 0; j < 4; ++j)
            acc[i][j] = (i32x4){0, 0, 0, 0};

    for (int kt = 0; kt < 16; ++kt) {
        __syncthreads();
        if (kt < 15) {
            #pragma unroll
            for (int c = 0; c < 4; ++c) {
                int o = c * 4096 + wv * 1024;
                const signed char* s = (o < 8192)
                    ? (Asrc + (size_t)(kt + 1) * 8192 + o + lane * 16)
                    : (Bsrc + (size_t)(kt + 1) * 8192 + (o - 8192) + lane * 16);
                gl_lds16(s, sbuf[(kt + 1) & 1] + o);
            }
        }
        const char* base = sbuf[kt & 1];
        i32x4 A[4], Bv[4];
        #pragma unroll
        for (int m = 0; m < 4; ++m)
            A[m] = *reinterpret_cast<const i32x4*>(base + wr * 4096 + m * 1024 + lane * 16);
        #pragma unroll
        for (int n = 0; n < 4; ++n)
            Bv[n] = *reinterpret_cast<const i32x4*>(base + 8192 + wc * 4096 + n * 1024 + lane * 16);
        #pragma unroll
        for (int m = 0; m < 4; ++m)
            #pragma unroll
            for (int n = 0; n < 4; ++n)
                acc[m][n] = __builtin_amdgcn_mfma_i32_16x16x64_i8(
                    A[m], Bv[n], acc[m][n], 0, 0, 0);
    }

    int spikes = 0;
    #pragma unroll
    for (int m = 0; m < 4; ++m) {
        const int h0l = h_idx * 128 + wr * 64 + m * 16 + g * 4;
        const int kt64 = h_idx * 2 + wr;
        const int k2lane = m * 16 + l15;
        float4 bias = *reinterpret_cast<const float4*>(b1 + h0l);
        float bj[4] = {bias.x, bias.y, bias.z, bias.w};
        #pragma unroll
        for (int n = 0; n < 4; ++n) {
            const int bt = b_panel * 8 + wc * 4 + n;
            unsigned pcode = 0;
            #pragma unroll
            for (int j = 0; j < 4; ++j) {
                float i1 = __fmul_rn((float)acc[m][n][j], 3.0517578125e-05f) + bj[j];
                float arg = fmaf(-0.1f, __builtin_amdgcn_rcpf(i1), 1.0f);
                float pf = ceilf(__log2f(arg) * -6.578813478960192f);
                int p = (int)pf;
                p = p < 1 ? 1 : (p > 21 ? 21 : p);
                int pe = (i1 >= 0.113843485f) ? p : 0;
                spikes += __popc(lutm[pe]);
                pcode |= (unsigned)pe << (8 * j);
            }
            const size_t rec = ((size_t)bt * 32 + kt64) * 64 + k2lane;
            *reinterpret_cast<unsigned int*>(M5 + rec * 16 + g * 4) = pcode;
        }
    }
    #pragma unroll
    for (int off = 32; off > 0; off >>= 1)
        spikes += __shfl_down(spikes, off);
    if (lane == 0) sred[wv] = spikes;
    __syncthreads();
    if (tid == 0)
        atomicAdd(spike_count, (unsigned int)(sred[0] + sred[1] + sred[2] + sred[3]));
}

// ---------------- K2: layer 2 i8 K=64; round-18 shell + spread-LUT/v_perm A-build ----
// 256 thr = 4 waves; wave tg owns 5 timesteps (t = 5tg..5tg+4) x 128 cols, 16 b/block.
// lutA[tg][p][repl 32] = spikes(p, 5tg+0..3) as 4 bytes; lutC[p][repl 32] = byte tgi =
// spike(p, 5tgi+4). addr = (p<<5)|lane&31 -> own bank (r19 lesson). Per pc byte: 2
// conflict-free ds_read_b32 (shared index); v_perm 4x4 transpose (r20-validated) + 3
// perms for the 5th t. Replaces ~210 VALU mask chain with ~80. Bit-exact vs r18.
__global__ __launch_bounds__(256, 2) void k_layer2_i8(
    const unsigned char* __restrict__ M5,
    const signed char* __restrict__ W2q,
    const float* __restrict__ b2,
    float* __restrict__ out)
{
    __shared__ __align__(16) char smem[32512];   // [0,18432) stage dbuf; [18432,29696) lutA; [29696,32512) lutC
    float* sm_f32 = (float*)smem;
    unsigned* lutA = (unsigned*)(smem + 18432);  // [tg(4)][p(22)][32]
    unsigned* lutC = (unsigned*)(smem + 29696);  // [p(22)][32]

    const int tid  = threadIdx.x;
    const int wv   = tid >> 6;        // 0..3
    const int tg   = wv;              // t in [tg*5, tg*5+5)
    const int lane = tid & 63;
    const int l15  = lane & 15;
    const int g    = lane >> 4;
    const int b0   = blockIdx.x * 16;
    const int t0   = tg * 5;
    const int lsl  = lane & 31;

    // init lutA: [tgi][p][repl]: bytes tl=0..3 = spike(p, 5tgi+tl)
    for (int e = tid; e < 2816; e += 256) {
        int tgi = e / 704;
        int p   = (e - tgi * 704) >> 5;
        unsigned v = 0;
        #pragma unroll
        for (int tl = 0; tl < 4; ++tl) {
            int t = tgi * 5 + tl;
            unsigned c = (p >= 1 && ((t + 1) % p) == 0) ? 1u : 0u;
            v |= c << (8 * tl);
        }
        lutA[e] = v;
    }
    // init lutC: [p][repl]: byte tgi = spike(p, 5tgi+4)
    for (int e = tid; e < 704; e += 256) {
        int p = e >> 5;
        unsigned v = 0;
        #pragma unroll
        for (int tgi = 0; tgi < 4; ++tgi) {
            int t = tgi * 5 + 4;
            unsigned c = (p >= 1 && ((t + 1) % p) == 0) ? 1u : 0u;
            v |= c << (8 * tgi);
        }
        lutC[e] = v;
    }

    const size_t m5blk = (size_t)blockIdx.x * 32768;   // bytes

    i32x4 acc[8][5];
    #pragma unroll
    for (int n = 0; n < 8; ++n)
        #pragma unroll
        for (int t = 0; t < 5; ++t)
            acc[n][t] = (i32x4){0, 0, 0, 0};

    // prologue: stage kt=0 into buf 0. 9 chunks of 1KB: [0..7]=w2, [8]=pcodes
    for (int c = wv; c < 9; c += 4) {
        const char* s = (c < 8) ? ((const char*)W2q + c * 1024)
                                : ((const char*)M5 + m5blk);
        gl_lds16(s + lane * 16, smem + c * 1024);
    }

    const unsigned* lA = lutA + tg * 704 + lsl;
    const unsigned* lC = lutC + lsl;
    const unsigned selz = 0x0C0C0000u | ((4u + (unsigned)tg) << 8) | (unsigned)tg;

    for (int kt = 0; kt < 32; ++kt) {
        __syncthreads();
        const int cb = (kt & 1) * 9216;
        if (kt < 31) {
            const int nb = ((kt + 1) & 1) * 9216;
            for (int c = wv; c < 9; c += 4) {
                const char* s = (c < 8)
                    ? ((const char*)W2q + (size_t)(kt + 1) * 8192 + c * 1024)
                    : ((const char*)M5 + m5blk + (size_t)(kt + 1) * 1024);
                gl_lds16(s + lane * 16, smem + nb + c * 1024);
            }
        }

        union { uint4 v; unsigned u[4]; } pc;
        pc.v = *reinterpret_cast<const uint4*>(smem + cb + 8192 + lane * 16);

        union { i32x4 v; unsigned u[4]; } A[5];
        #pragma unroll
        for (int g2 = 0; g2 < 4; ++g2) {
            unsigned w = pc.u[g2];
            unsigned i0 = ((w      ) & 0xffu) << 5;
            unsigned i1 = ((w >>  8) & 0xffu) << 5;
            unsigned i2 = ((w >> 16) & 0xffu) << 5;
            unsigned i3 = ( w >> 24         ) << 5;
            unsigned q0 = lA[i0], q1 = lA[i1], q2 = lA[i2], q3 = lA[i3];
            unsigned c0 = lC[i0], c1 = lC[i1], c2 = lC[i2], c3 = lC[i3];
            // 4x4 byte transpose (validated r20); A byte order {j0,j2,j1,j3} = w2q perm
            unsigned u01 = __builtin_amdgcn_perm(q2, q0, 0x05010400u); // [q0.0,q2.0,q0.1,q2.1]
            unsigned u23 = __builtin_amdgcn_perm(q3, q1, 0x05010400u);
            unsigned v01 = __builtin_amdgcn_perm(q2, q0, 0x07030602u); // [q0.2,q2.2,q0.3,q2.3]
            unsigned v23 = __builtin_amdgcn_perm(q3, q1, 0x07030602u);
            A[0].u[g2] = __builtin_amdgcn_perm(u23, u01, 0x05040100u);
            A[1].u[g2] = __builtin_amdgcn_perm(u23, u01, 0x07060302u);
            A[2].u[g2] = __builtin_amdgcn_perm(v23, v01, 0x05040100u);
            A[3].u[g2] = __builtin_amdgcn_perm(v23, v01, 0x07060302u);
            // 5th timestep: byte tg of each lutC word
            unsigned z01 = __builtin_amdgcn_perm(c2, c0, selz);        // [c0.tg,c2.tg,0,0]
            unsigned z23 = __builtin_amdgcn_perm(c3, c1, selz);
            A[4].u[g2] = __builtin_amdgcn_perm(z23, z01, 0x05040100u);
        }

        i32x4 Bv[8];
        #pragma unroll
        for (int nt = 0; nt < 8; ++nt)
            Bv[nt] = *reinterpret_cast<const i32x4*>(smem + cb + nt * 1024 + lane * 16);
        #pragma unroll
        for (int tl = 0; tl < 5; ++tl)
            #pragma unroll
            for (int nt = 0; nt < 8; ++nt)
                acc[nt][tl] = __builtin_amdgcn_mfma_i32_16x16x64_i8(
                    A[tl].v, Bv[nt], acc[nt][tl], 0, 0, 0);
    }

    // epilogue: 8 chunks of 16 cols; transpose through LDS, then LIF per (b,c)
    #pragma unroll
    for (int q = 0; q < 8; ++q) {
        __syncthreads();
        #pragma unroll
        for (int tl = 0; tl < 5; ++tl)
            #pragma unroll
            for (int j = 0; j < 4; ++j)
                sm_f32[((g * 4 + j) * 17 + l15) * 21 + (t0 + tl)] = (float)acc[q][tl][j];
        __syncthreads();
        {
            const int bl  = tid >> 4;     // 0..15
            const int c16 = tid & 15;
            const int c   = q * 16 + c16;
            const float bias = b2[c];
            float u2 = 0.0f; int cnt = 0;
            #pragma unroll
            for (int t = 0; t < T_STEPS; ++t) {
                float X = __fadd_rn(__fmul_rn(sm_f32[(bl * 17 + c16) * 21 + t], 0.0009765625f), bias);
                u2 = __fadd_rn(__fmul_rn(0.9f, u2), X);
                if (u2 >= 1.0f) { cnt++; u2 = 0.0f; }
            }
            out[(size_t)(b0 + bl) * C_SZ + c] = (float)cnt / 20.0f;
        }
    }
}

// ---------------- K3: mean_spikes = total / (B * T) ----------------
__global__ void k_finalize(const unsigned int* __restrict__ spike_count, float* __restrict__ out) {
    out[(size_t)B_SZ * C_SZ] = (float)(*spike_count) / (float)((size_t)B_SZ * T_STEPS);
}

extern "C" void kernel_launch(void* const* d_in, const int* in_sizes, int n_in,
                              void* d_out, int out_size, void* d_ws, size_t ws_size,
                              hipStream_t stream) {
    const float* x  = (const float*)d_in[0];
    const float* W1 = (const float*)d_in[1];
    const float* b1 = (const float*)d_in[2];
    const float* W2 = (const float*)d_in[3];
    const float* b2 = (const float*)d_in[4];
    float* out = (float*)d_out;

    char* ws = (char*)d_ws;
    const size_t m5_b   = (size_t)B_SZ * H_SZ;       // 33.6 MB
    const size_t xfi_b  = (size_t)B_SZ * D_SZ;       // 16.8 MB
    const size_t w1fi_b = (size_t)H_SZ * D_SZ;       //  2.1 MB
    const size_t w2q_b  = (size_t)C_SZ * H_SZ;       //  0.26 MB

    size_t off = 0;
    unsigned char*  M5   = (unsigned char*)(ws + off);  off += m5_b;
    signed char*    xfi  = (signed char*)(ws + off);    off += xfi_b;
    signed char*    w1fi = (signed char*)(ws + off);    off += w1fi_b;
    signed char*    w2q  = (signed char*)(ws + off);    off += w2q_b;
    unsigned int* counter = (unsigned int*)(ws + off);  off += 256;

    hipMemsetAsync(counter, 0, sizeof(unsigned int), stream);

    k_w1fragi8<<<512, 256, 0, stream>>>(W1, w1fi);   // 131072 threads EXACT
    k_w2fragi8<<<64, 256, 0, stream>>>(W2, w2q);     // 16384 threads EXACT
    k_xfragi8<<<4096, 256, 0, stream>>>(x, xfi);     // 1048576 threads EXACT

    k_gemm1_i8<<<2048, 256, 0, stream>>>(xfi, w1fi, b1, M5, counter);

    k_layer2_i8<<<B_SZ / 16, 256, 0, stream>>>(M5, w2q, b2, out);

    k_finalize<<<1, 1, 0, stream>>>(counter, out);
}

// Round 22
// 181.652 us; speedup vs baseline: 1.4653x; 1.0345x over previous
//
#include <hip/hip_runtime.h>

#define B_SZ 16384
#define D_SZ 1024
#define H_SZ 2048
#define C_SZ 128
#define T_STEPS 20

typedef __attribute__((ext_vector_type(4))) float f32x4;
typedef __attribute__((ext_vector_type(4))) int   i32x4;

__device__ __forceinline__ signed char to_i8(float f, float s) {
    float v = rintf(s * f);
    v = v > 127.0f ? 127.0f : (v < -127.0f ? -127.0f : v);
    return (signed char)(int)v;
}

__device__ __forceinline__ void gl_lds16(const void* g, void* l) {
    __builtin_amdgcn_global_load_lds(
        (const __attribute__((address_space(1))) unsigned int*)g,
        (__attribute__((address_space(3))) unsigned int*)l, 16, 0, 0);
}

// ---------------- W1 -> i8 frags: [p(16)][kt(16)][wr(2)][m(4)][lane(64)][16B] --------
__global__ void k_w1fragi8(const float* __restrict__ W1, signed char* __restrict__ w1f) {
    int idx = blockIdx.x * blockDim.x + threadIdx.x;   // 0..131071
    int lane = idx & 63;
    int m    = (idx >> 6) & 3;
    int wr   = (idx >> 8) & 1;
    int kt   = (idx >> 9) & 15;
    int p    = idx >> 13;
    int h = p * 128 + wr * 64 + m * 16 + (lane & 15);
    int k = kt * 64 + (lane >> 4) * 16;
    const float* src = W1 + (size_t)h * D_SZ + k;
    union { signed char b[16]; uint4 u; } q;
    #pragma unroll
    for (int q4 = 0; q4 < 4; ++q4) {
        float4 v = *reinterpret_cast<const float4*>(src + q4 * 4);
        q.b[q4 * 4 + 0] = to_i8(v.x, 1024.0f);
        q.b[q4 * 4 + 1] = to_i8(v.y, 1024.0f);
        q.b[q4 * 4 + 2] = to_i8(v.z, 1024.0f);
        q.b[q4 * 4 + 3] = to_i8(v.w, 1024.0f);
    }
    size_t off = (size_t)p * 131072 + (size_t)kt * 8192 + wr * 4096 + m * 1024 + lane * 16;
    *reinterpret_cast<uint4*>(w1f + off) = q.u;
}

// ---------------- x -> i8 frags: [bp(128)][kt(16)][wc(2)][n(4)][lane(64)][16B] -------
__global__ void k_xfragi8(const float* __restrict__ x, signed char* __restrict__ xf) {
    int idx = blockIdx.x * blockDim.x + threadIdx.x;   // 0..1048575
    int lane = idx & 63;
    int n    = (idx >> 6) & 3;
    int wc   = (idx >> 8) & 1;
    int kt   = (idx >> 9) & 15;
    int bp   = idx >> 13;
    int b = bp * 128 + wc * 64 + n * 16 + (lane & 15);
    int k = kt * 64 + (lane >> 4) * 16;
    const float* src = x + (size_t)b * D_SZ + k;
    union { signed char b[16]; uint4 u; } q;
    #pragma unroll
    for (int q4 = 0; q4 < 4; ++q4) {
        float4 v = *reinterpret_cast<const float4*>(src + q4 * 4);
        q.b[q4 * 4 + 0] = to_i8(v.x, 32.0f);
        q.b[q4 * 4 + 1] = to_i8(v.y, 32.0f);
        q.b[q4 * 4 + 2] = to_i8(v.z, 32.0f);
        q.b[q4 * 4 + 3] = to_i8(v.w, 32.0f);
    }
    size_t off = (size_t)bp * 131072 + (size_t)kt * 8192 + wc * 4096 + n * 1024 + lane * 16;
    *reinterpret_cast<uint4*>(xf + off) = q.u;
}

// ---------------- W2 -> i8 frags: [kt64(32)][nt(8)][lane(64)][16B], k-perm baked -----
__global__ void k_w2fragi8(const float* __restrict__ W2, signed char* __restrict__ w2q) {
    const int perm4[4] = {0, 2, 1, 3};
    int idx = blockIdx.x * blockDim.x + threadIdx.x;   // 0..16383
    int lane = idx & 63;
    int nt   = (idx >> 6) & 7;
    int kt   = idx >> 9;                               // 0..31
    int c = nt * 16 + (lane & 15);
    int hbase = kt * 64 + (lane >> 4) * 16;
    const float* src = W2 + (size_t)c * H_SZ + hbase;
    float f[16];
    #pragma unroll
    for (int q4 = 0; q4 < 4; ++q4) {
        float4 v = *reinterpret_cast<const float4*>(src + q4 * 4);
        f[q4 * 4 + 0] = v.x; f[q4 * 4 + 1] = v.y; f[q4 * 4 + 2] = v.z; f[q4 * 4 + 3] = v.w;
    }
    union { signed char b[16]; uint4 u; } q;
    #pragma unroll
    for (int j = 0; j < 16; ++j) {
        int k = (j & ~3) + perm4[j & 3];
        q.b[j] = to_i8(f[k], 1024.0f);
    }
    *reinterpret_cast<uint4*>(w2q + (size_t)idx * 16) = q.u;
}

// ---------------- K1: LDS-staged i8 GEMM + closed-form LIF, 1-byte p-code masks ------
// (round-18 kernel, unchanged)
__global__ __launch_bounds__(256, 2) void k_gemm1_i8(
    const signed char* __restrict__ xf,
    const signed char* __restrict__ w1f,
    const float* __restrict__ b1,
    unsigned char* __restrict__ M5,
    unsigned int* __restrict__ spike_count)
{
    __shared__ unsigned lutm[22];
    __shared__ int sred[4];
    __shared__ __align__(16) char sbuf[2][16384];   // [buf][A 8KB | B 8KB]
    const int tid  = threadIdx.x;
    if (tid < 22) {
        unsigned m = 0;
        if (tid >= 1 && tid <= 20)
            for (int t = tid - 1; t < T_STEPS; t += tid) m |= 1u << t;
        lutm[tid] = m;
    }

    const int wv   = tid >> 6;
    const int lane = tid & 63;
    const int l15  = lane & 15;
    const int g    = lane >> 4;
    const int wr   = wv >> 1;
    const int wc   = wv & 1;

    const int wg    = blockIdx.x;
    const int xcd   = wg & 7;
    const int local = wg >> 3;
    const int sc    = local >> 4;
    const int sl    = local & 15;
    const int b_panel = xcd * 16 + (sc >> 2) * 4 + (sl >> 2);
    const int h_idx   = (sc & 3) * 4 + (sl & 3);

    const signed char* Asrc = w1f + (size_t)h_idx * 131072;
    const signed char* Bsrc = xf + (size_t)b_panel * 131072;

    #pragma unroll
    for (int c = 0; c < 4; ++c) {
        int o = c * 4096 + wv * 1024;
        const signed char* s = (o < 8192) ? (Asrc + o + lane * 16)
                                          : (Bsrc + (o - 8192) + lane * 16);
        gl_lds16(s, sbuf[0] + o);
    }

    i32x4 acc[4][4];
    #pragma unroll
    for (int i = 0; i < 4; ++i)
        #pragma unroll
        for (int j = 0; j < 4; ++j)
            acc[i][j] = (i32x4){0, 0, 0, 0};

    for (int kt = 0; kt < 16; ++kt) {
        __syncthreads();
        if (kt < 15) {
            #pragma unroll
            for (int c = 0; c < 4; ++c) {
                int o = c * 4096 + wv * 1024;
                const signed char* s = (o < 8192)
                    ? (Asrc + (size_t)(kt + 1) * 8192 + o + lane * 16)
                    : (Bsrc + (size_t)(kt + 1) * 8192 + (o - 8192) + lane * 16);
                gl_lds16(s, sbuf[(kt + 1) & 1] + o);
            }
        }
        const char* base = sbuf[kt & 1];
        i32x4 A[4], Bv[4];
        #pragma unroll
        for (int m = 0; m < 4; ++m)
            A[m] = *reinterpret_cast<const i32x4*>(base + wr * 4096 + m * 1024 + lane * 16);
        #pragma unroll
        for (int n = 0; n < 4; ++n)
            Bv[n] = *reinterpret_cast<const i32x4*>(base + 8192 + wc * 4096 + n * 1024 + lane * 16);
        #pragma unroll
        for (int m = 0; m < 4; ++m)
            #pragma unroll
            for (int n = 0; n < 4; ++n)
                acc[m][n] = __builtin_amdgcn_mfma_i32_16x16x64_i8(
                    A[m], Bv[n], acc[m][n], 0, 0, 0);
    }

    int spikes = 0;
    #pragma unroll
    for (int m = 0; m < 4; ++m) {
        const int h0l = h_idx * 128 + wr * 64 + m * 16 + g * 4;
        const int kt64 = h_idx * 2 + wr;
        const int k2lane = m * 16 + l15;
        float4 bias = *reinterpret_cast<const float4*>(b1 + h0l);
        float bj[4] = {bias.x, bias.y, bias.z, bias.w};
        #pragma unroll
        for (int n = 0; n < 4; ++n) {
            const int bt = b_panel * 8 + wc * 4 + n;
            unsigned pcode = 0;
            #pragma unroll
            for (int j = 0; j < 4; ++j) {
                float i1 = __fmul_rn((float)acc[m][n][j], 3.0517578125e-05f) + bj[j];
                float arg = fmaf(-0.1f, __builtin_amdgcn_rcpf(i1), 1.0f);
                float pf = ceilf(__log2f(arg) * -6.578813478960192f);
                int p = (int)pf;
                p = p < 1 ? 1 : (p > 21 ? 21 : p);
                int pe = (i1 >= 0.113843485f) ? p : 0;
                spikes += __popc(lutm[pe]);
                pcode |= (unsigned)pe << (8 * j);
            }
            const size_t rec = ((size_t)bt * 32 + kt64) * 64 + k2lane;
            *reinterpret_cast<unsigned int*>(M5 + rec * 16 + g * 4) = pcode;
        }
    }
    #pragma unroll
    for (int off = 32; off > 0; off >>= 1)
        spikes += __shfl_down(spikes, off);
    if (lane == 0) sred[wv] = spikes;
    __syncthreads();
    if (tid == 0)
        atomicAdd(spike_count, (unsigned int)(sred[0] + sred[1] + sred[2] + sred[3]));
}

// ---------------- K2: layer 2 i8 K=64; fused b64 spread-LUT + v_perm A-build ---------
// 256 thr = 4 waves x 5 timesteps (r18 shell). lut8[tg][p][repl 32] = 8B entry:
// bytes 0-3 = spike(p, 5tg+0..3), byte 4 = spike(p, 5tg+4). ONE ds_read_b64 per
// pcode byte (was 2 b32 in r21): -16 LDS instr, -16 VALU per kt. addr = p*256 +
// lsl*8 -> bank 2*lsl mod 32, 2-way aliasing = free (m136). Transpose = the
// r20/r21-validated 11-perm pattern. Bit-exact vs r21.
__global__ __launch_bounds__(256, 2) void k_layer2_i8(
    const unsigned char* __restrict__ M5,
    const signed char* __restrict__ W2q,
    const float* __restrict__ b2,
    float* __restrict__ out)
{
    __shared__ __align__(16) char smem[40960];   // [0,18432) stage dbuf; [18432,40960) lut8; epi overlaps
    float* sm_f32 = (float*)smem;
    uint2* lut8 = (uint2*)(smem + 18432);        // [tg(4)][p(22)][repl(32)] uint2

    const int tid  = threadIdx.x;
    const int wv   = tid >> 6;        // 0..3
    const int tg   = wv;              // t in [tg*5, tg*5+5)
    const int lane = tid & 63;
    const int l15  = lane & 15;
    const int g    = lane >> 4;
    const int b0   = blockIdx.x * 16;
    const int t0   = tg * 5;
    const int lsl  = lane & 31;

    // init lut8: [tgi][p][repl]: lo bytes tl=0..3 = spike(p,5tgi+tl); hi byte0 = spike(p,5tgi+4)
    for (int e = tid; e < 2816; e += 256) {
        int tgi = e / 704;
        int p   = (e - tgi * 704) >> 5;
        unsigned lo = 0;
        #pragma unroll
        for (int tl = 0; tl < 4; ++tl) {
            int t = tgi * 5 + tl;
            unsigned c = (p >= 1 && ((t + 1) % p) == 0) ? 1u : 0u;
            lo |= c << (8 * tl);
        }
        int t4 = tgi * 5 + 4;
        unsigned hi = (p >= 1 && ((t4 + 1) % p) == 0) ? 1u : 0u;
        lut8[e] = make_uint2(lo, hi);
    }

    const size_t m5blk = (size_t)blockIdx.x * 32768;   // bytes

    i32x4 acc[8][5];
    #pragma unroll
    for (int n = 0; n < 8; ++n)
        #pragma unroll
        for (int t = 0; t < 5; ++t)
            acc[n][t] = (i32x4){0, 0, 0, 0};

    // prologue: stage kt=0 into buf 0. 9 chunks of 1KB: [0..7]=w2, [8]=pcodes
    for (int c = wv; c < 9; c += 4) {
        const char* s = (c < 8) ? ((const char*)W2q + c * 1024)
                                : ((const char*)M5 + m5blk);
        gl_lds16(s + lane * 16, smem + c * 1024);
    }

    const uint2* l8 = lut8 + tg * 704 + lsl;   // + p*32 per lookup

    for (int kt = 0; kt < 32; ++kt) {
        __syncthreads();
        const int cb = (kt & 1) * 9216;
        if (kt < 31) {
            const int nb = ((kt + 1) & 1) * 9216;
            for (int c = wv; c < 9; c += 4) {
                const char* s = (c < 8)
                    ? ((const char*)W2q + (size_t)(kt + 1) * 8192 + c * 1024)
                    : ((const char*)M5 + m5blk + (size_t)(kt + 1) * 1024);
                gl_lds16(s + lane * 16, smem + nb + c * 1024);
            }
        }

        union { uint4 v; unsigned u[4]; } pc;
        pc.v = *reinterpret_cast<const uint4*>(smem + cb + 8192 + lane * 16);

        union { i32x4 v; unsigned u[4]; } A[5];
        #pragma unroll
        for (int g2 = 0; g2 < 4; ++g2) {
            unsigned w = pc.u[g2];
            uint2 q0 = l8[((w      ) & 0xffu) << 5];
            uint2 q1 = l8[((w >>  8) & 0xffu) << 5];
            uint2 q2 = l8[((w >> 16) & 0xffu) << 5];
            uint2 q3 = l8[( w >> 24         ) << 5];
            // 4x4 byte transpose (validated r20); A byte order {j0,j2,j1,j3} = w2q perm
            unsigned u01 = __builtin_amdgcn_perm(q2.x, q0.x, 0x05010400u);
            unsigned u23 = __builtin_amdgcn_perm(q3.x, q1.x, 0x05010400u);
            unsigned v01 = __builtin_amdgcn_perm(q2.x, q0.x, 0x07030602u);
            unsigned v23 = __builtin_amdgcn_perm(q3.x, q1.x, 0x07030602u);
            A[0].u[g2] = __builtin_amdgcn_perm(u23, u01, 0x05040100u);
            A[1].u[g2] = __builtin_amdgcn_perm(u23, u01, 0x07060302u);
            A[2].u[g2] = __builtin_amdgcn_perm(v23, v01, 0x05040100u);
            A[3].u[g2] = __builtin_amdgcn_perm(v23, v01, 0x07060302u);
            // 5th timestep from hi words (byte 0 of each)
            unsigned z01 = __builtin_amdgcn_perm(q2.y, q0.y, 0x0C0C0400u);
            unsigned z23 = __builtin_amdgcn_perm(q3.y, q1.y, 0x0C0C0400u);
            A[4].u[g2] = __builtin_amdgcn_perm(z23, z01, 0x05040100u);
        }

        i32x4 Bv[8];
        #pragma unroll
        for (int nt = 0; nt < 8; ++nt)
            Bv[nt] = *reinterpret_cast<const i32x4*>(smem + cb + nt * 1024 + lane * 16);
        #pragma unroll
        for (int tl = 0; tl < 5; ++tl)
            #pragma unroll
            for (int nt = 0; nt < 8; ++nt)
                acc[nt][tl] = __builtin_amdgcn_mfma_i32_16x16x64_i8(
                    A[tl].v, Bv[nt], acc[nt][tl], 0, 0, 0);
    }

    // epilogue: 8 chunks of 16 cols; transpose through LDS, then LIF per (b,c)
    #pragma unroll
    for (int q = 0; q < 8; ++q) {
        __syncthreads();
        #pragma unroll
        for (int tl = 0; tl < 5; ++tl)
            #pragma unroll
            for (int j = 0; j < 4; ++j)
                sm_f32[((g * 4 + j) * 17 + l15) * 21 + (t0 + tl)] = (float)acc[q][tl][j];
        __syncthreads();
        {
            const int bl  = tid >> 4;     // 0..15
            const int c16 = tid & 15;
            const int c   = q * 16 + c16;
            const float bias = b2[c];
            float u2 = 0.0f; int cnt = 0;
            #pragma unroll
            for (int t = 0; t < T_STEPS; ++t) {
                float X = __fadd_rn(__fmul_rn(sm_f32[(bl * 17 + c16) * 21 + t], 0.0009765625f), bias);
                u2 = __fadd_rn(__fmul_rn(0.9f, u2), X);
                if (u2 >= 1.0f) { cnt++; u2 = 0.0f; }
            }
            out[(size_t)(b0 + bl) * C_SZ + c] = (float)cnt / 20.0f;
        }
    }
}

// ---------------- K3: mean_spikes = total / (B * T) ----------------
__global__ void k_finalize(const unsigned int* __restrict__ spike_count, float* __restrict__ out) {
    out[(size_t)B_SZ * C_SZ] = (float)(*spike_count) / (float)((size_t)B_SZ * T_STEPS);
}

extern "C" void kernel_launch(void* const* d_in, const int* in_sizes, int n_in,
                              void* d_out, int out_size, void* d_ws, size_t ws_size,
                              hipStream_t stream) {
    const float* x  = (const float*)d_in[0];
    const float* W1 = (const float*)d_in[1];
    const float* b1 = (const float*)d_in[2];
    const float* W2 = (const float*)d_in[3];
    const float* b2 = (const float*)d_in[4];
    float* out = (float*)d_out;

    char* ws = (char*)d_ws;
    const size_t m5_b   = (size_t)B_SZ * H_SZ;       // 33.6 MB
    const size_t xfi_b  = (size_t)B_SZ * D_SZ;       // 16.8 MB
    const size_t w1fi_b = (size_t)H_SZ * D_SZ;       //  2.1 MB
    const size_t w2q_b  = (size_t)C_SZ * H_SZ;       //  0.26 MB

    size_t off = 0;
    unsigned char*  M5   = (unsigned char*)(ws + off);  off += m5_b;
    signed char*    xfi  = (signed char*)(ws + off);    off += xfi_b;
    signed char*    w1fi = (signed char*)(ws + off);    off += w1fi_b;
    signed char*    w2q  = (signed char*)(ws + off);    off += w2q_b;
    unsigned int* counter = (unsigned int*)(ws + off);  off += 256;

    hipMemsetAsync(counter, 0, sizeof(unsigned int), stream);

    k_w1fragi8<<<512, 256, 0, stream>>>(W1, w1fi);   // 131072 threads EXACT
    k_w2fragi8<<<64, 256, 0, stream>>>(W2, w2q);     // 16384 threads EXACT
    k_xfragi8<<<4096, 256, 0, stream>>>(x, xfi);     // 1048576 threads EXACT

    k_gemm1_i8<<<2048, 256, 0, stream>>>(xfi, w1fi, b1, M5, counter);

    k_layer2_i8<<<B_SZ / 16, 256, 0, stream>>>(M5, w2q, b2, out);

    k_finalize<<<1, 1, 0, stream>>>(counter, out);
}

// Round 23
// 180.082 us; speedup vs baseline: 1.4780x; 1.0087x over previous
//
#include <hip/hip_runtime.h>

#define B_SZ 16384
#define D_SZ 1024
#define H_SZ 2048
#define C_SZ 128
#define T_STEPS 20

typedef __attribute__((ext_vector_type(4))) float f32x4;
typedef __attribute__((ext_vector_type(4))) int   i32x4;

__device__ __forceinline__ signed char to_i8(float f, float s) {
    float v = rintf(s * f);
    v = v > 127.0f ? 127.0f : (v < -127.0f ? -127.0f : v);
    return (signed char)(int)v;
}

__device__ __forceinline__ void gl_lds16(const void* g, void* l) {
    __builtin_amdgcn_global_load_lds(
        (const __attribute__((address_space(1))) unsigned int*)g,
        (__attribute__((address_space(3))) unsigned int*)l, 16, 0, 0);
}

// ---------------- W1 -> i8 frags: [p(16)][kt(16)][wr(2)][m(4)][lane(64)][16B] --------
__global__ void k_w1fragi8(const float* __restrict__ W1, signed char* __restrict__ w1f) {
    int idx = blockIdx.x * blockDim.x + threadIdx.x;   // 0..131071
    int lane = idx & 63;
    int m    = (idx >> 6) & 3;
    int wr   = (idx >> 8) & 1;
    int kt   = (idx >> 9) & 15;
    int p    = idx >> 13;
    int h = p * 128 + wr * 64 + m * 16 + (lane & 15);
    int k = kt * 64 + (lane >> 4) * 16;
    const float* src = W1 + (size_t)h * D_SZ + k;
    union { signed char b[16]; uint4 u; } q;
    #pragma unroll
    for (int q4 = 0; q4 < 4; ++q4) {
        float4 v = *reinterpret_cast<const float4*>(src + q4 * 4);
        q.b[q4 * 4 + 0] = to_i8(v.x, 1024.0f);
        q.b[q4 * 4 + 1] = to_i8(v.y, 1024.0f);
        q.b[q4 * 4 + 2] = to_i8(v.z, 1024.0f);
        q.b[q4 * 4 + 3] = to_i8(v.w, 1024.0f);
    }
    size_t off = (size_t)p * 131072 + (size_t)kt * 8192 + wr * 4096 + m * 1024 + lane * 16;
    *reinterpret_cast<uint4*>(w1f + off) = q.u;
}

// ---------------- x -> i8 frags: [bp(128)][kt(16)][wc(2)][n(4)][lane(64)][16B] -------
__global__ void k_xfragi8(const float* __restrict__ x, signed char* __restrict__ xf) {
    int idx = blockIdx.x * blockDim.x + threadIdx.x;   // 0..1048575
    int lane = idx & 63;
    int n    = (idx >> 6) & 3;
    int wc   = (idx >> 8) & 1;
    int kt   = (idx >> 9) & 15;
    int bp   = idx >> 13;
    int b = bp * 128 + wc * 64 + n * 16 + (lane & 15);
    int k = kt * 64 + (lane >> 4) * 16;
    const float* src = x + (size_t)b * D_SZ + k;
    union { signed char b[16]; uint4 u; } q;
    #pragma unroll
    for (int q4 = 0; q4 < 4; ++q4) {
        float4 v = *reinterpret_cast<const float4*>(src + q4 * 4);
        q.b[q4 * 4 + 0] = to_i8(v.x, 32.0f);
        q.b[q4 * 4 + 1] = to_i8(v.y, 32.0f);
        q.b[q4 * 4 + 2] = to_i8(v.z, 32.0f);
        q.b[q4 * 4 + 3] = to_i8(v.w, 32.0f);
    }
    size_t off = (size_t)bp * 131072 + (size_t)kt * 8192 + wc * 4096 + n * 1024 + lane * 16;
    *reinterpret_cast<uint4*>(xf + off) = q.u;
}

// ---------------- W2 -> i8 frags: [kt64(32)][nt(8)][lane(64)][16B], k-perm baked -----
__global__ void k_w2fragi8(const float* __restrict__ W2, signed char* __restrict__ w2q) {
    const int perm4[4] = {0, 2, 1, 3};
    int idx = blockIdx.x * blockDim.x + threadIdx.x;   // 0..16383
    int lane = idx & 63;
    int nt   = (idx >> 6) & 7;
    int kt   = idx >> 9;                               // 0..31
    int c = nt * 16 + (lane & 15);
    int hbase = kt * 64 + (lane >> 4) * 16;
    const float* src = W2 + (size_t)c * H_SZ + hbase;
    float f[16];
    #pragma unroll
    for (int q4 = 0; q4 < 4; ++q4) {
        float4 v = *reinterpret_cast<const float4*>(src + q4 * 4);
        f[q4 * 4 + 0] = v.x; f[q4 * 4 + 1] = v.y; f[q4 * 4 + 2] = v.z; f[q4 * 4 + 3] = v.w;
    }
    union { signed char b[16]; uint4 u; } q;
    #pragma unroll
    for (int j = 0; j < 16; ++j) {
        int k = (j & ~3) + perm4[j & 3];
        q.b[j] = to_i8(f[k], 1024.0f);
    }
    *reinterpret_cast<uint4*>(w2q + (size_t)idx * 16) = q.u;
}

// ---------------- K1: LDS-staged i8 GEMM + closed-form LIF, 1-byte p-code masks ------
// launch_bounds(256,3): request 3 waves/SIMD (live set ~136 regs fits 3x; r17-r22
// settled at 2 waves -> L2 staging latency under-covered, MfmaUtil 11.5%).
__global__ __launch_bounds__(256, 3) void k_gemm1_i8(
    const signed char* __restrict__ xf,
    const signed char* __restrict__ w1f,
    const float* __restrict__ b1,
    unsigned char* __restrict__ M5,
    unsigned int* __restrict__ spike_count)
{
    __shared__ unsigned lutm[22];
    __shared__ int sred[4];
    __shared__ __align__(16) char sbuf[2][16384];   // [buf][A 8KB | B 8KB]
    const int tid  = threadIdx.x;
    if (tid < 22) {
        unsigned m = 0;
        if (tid >= 1 && tid <= 20)
            for (int t = tid - 1; t < T_STEPS; t += tid) m |= 1u << t;
        lutm[tid] = m;
    }

    const int wv   = tid >> 6;
    const int lane = tid & 63;
    const int l15  = lane & 15;
    const int g    = lane >> 4;
    const int wr   = wv >> 1;
    const int wc   = wv & 1;

    const int wg    = blockIdx.x;
    const int xcd   = wg & 7;
    const int local = wg >> 3;
    const int sc    = local >> 4;
    const int sl    = local & 15;
    const int b_panel = xcd * 16 + (sc >> 2) * 4 + (sl >> 2);
    const int h_idx   = (sc & 3) * 4 + (sl & 3);

    const signed char* Asrc = w1f + (size_t)h_idx * 131072;
    const signed char* Bsrc = xf + (size_t)b_panel * 131072;

    #pragma unroll
    for (int c = 0; c < 4; ++c) {
        int o = c * 4096 + wv * 1024;
        const signed char* s = (o < 8192) ? (Asrc + o + lane * 16)
                                          : (Bsrc + (o - 8192) + lane * 16);
        gl_lds16(s, sbuf[0] + o);
    }

    i32x4 acc[4][4];
    #pragma unroll
    for (int i = 0; i < 4; ++i)
        #pragma unroll
        for (int j = 0; j < 4; ++j)
            acc[i][j] = (i32x4){0, 0, 0, 0};

    for (int kt = 0; kt < 16; ++kt) {
        __syncthreads();
        if (kt < 15) {
            #pragma unroll
            for (int c = 0; c < 4; ++c) {
                int o = c * 4096 + wv * 1024;
                const signed char* s = (o < 8192)
                    ? (Asrc + (size_t)(kt + 1) * 8192 + o + lane * 16)
                    : (Bsrc + (size_t)(kt + 1) * 8192 + (o - 8192) + lane * 16);
                gl_lds16(s, sbuf[(kt + 1) & 1] + o);
            }
        }
        const char* base = sbuf[kt & 1];
        i32x4 A[4], Bv[4];
        #pragma unroll
        for (int m = 0; m < 4; ++m)
            A[m] = *reinterpret_cast<const i32x4*>(base + wr * 4096 + m * 1024 + lane * 16);
        #pragma unroll
        for (int n = 0; n < 4; ++n)
            Bv[n] = *reinterpret_cast<const i32x4*>(base + 8192 + wc * 4096 + n * 1024 + lane * 16);
        #pragma unroll
        for (int m = 0; m < 4; ++m)
            #pragma unroll
            for (int n = 0; n < 4; ++n)
                acc[m][n] = __builtin_amdgcn_mfma_i32_16x16x64_i8(
                    A[m], Bv[n], acc[m][n], 0, 0, 0);
    }

    int spikes = 0;
    #pragma unroll
    for (int m = 0; m < 4; ++m) {
        const int h0l = h_idx * 128 + wr * 64 + m * 16 + g * 4;
        const int kt64 = h_idx * 2 + wr;
        const int k2lane = m * 16 + l15;
        float4 bias = *reinterpret_cast<const float4*>(b1 + h0l);
        float bj[4] = {bias.x, bias.y, bias.z, bias.w};
        #pragma unroll
        for (int n = 0; n < 4; ++n) {
            const int bt = b_panel * 8 + wc * 4 + n;
            unsigned pcode = 0;
            #pragma unroll
            for (int j = 0; j < 4; ++j) {
                float i1 = __fmul_rn((float)acc[m][n][j], 3.0517578125e-05f) + bj[j];
                float arg = fmaf(-0.1f, __builtin_amdgcn_rcpf(i1), 1.0f);
                float pf = ceilf(__log2f(arg) * -6.578813478960192f);
                int p = (int)pf;
                p = p < 1 ? 1 : (p > 21 ? 21 : p);
                int pe = (i1 >= 0.113843485f) ? p : 0;
                spikes += __popc(lutm[pe]);
                pcode |= (unsigned)pe << (8 * j);
            }
            const size_t rec = ((size_t)bt * 32 + kt64) * 64 + k2lane;
            *reinterpret_cast<unsigned int*>(M5 + rec * 16 + g * 4) = pcode;
        }
    }
    #pragma unroll
    for (int off = 32; off > 0; off >>= 1)
        spikes += __shfl_down(spikes, off);
    if (lane == 0) sred[wv] = spikes;
    __syncthreads();
    if (tid == 0)
        atomicAdd(spike_count, (unsigned int)(sred[0] + sred[1] + sred[2] + sred[3]));
}

// ---------------- K2: layer 2 i8 K=64; fused b64 spread-LUT + v_perm A-build ---------
// (round-22 kernel, unchanged — 85% of i8 MFMA roofline)
__global__ __launch_bounds__(256, 2) void k_layer2_i8(
    const unsigned char* __restrict__ M5,
    const signed char* __restrict__ W2q,
    const float* __restrict__ b2,
    float* __restrict__ out)
{
    __shared__ __align__(16) char smem[40960];   // [0,18432) stage dbuf; [18432,40960) lut8; epi overlaps
    float* sm_f32 = (float*)smem;
    uint2* lut8 = (uint2*)(smem + 18432);        // [tg(4)][p(22)][repl(32)] uint2

    const int tid  = threadIdx.x;
    const int wv   = tid >> 6;        // 0..3
    const int tg   = wv;              // t in [tg*5, tg*5+5)
    const int lane = tid & 63;
    const int l15  = lane & 15;
    const int g    = lane >> 4;
    const int b0   = blockIdx.x * 16;
    const int t0   = tg * 5;
    const int lsl  = lane & 31;

    for (int e = tid; e < 2816; e += 256) {
        int tgi = e / 704;
        int p   = (e - tgi * 704) >> 5;
        unsigned lo = 0;
        #pragma unroll
        for (int tl = 0; tl < 4; ++tl) {
            int t = tgi * 5 + tl;
            unsigned c = (p >= 1 && ((t + 1) % p) == 0) ? 1u : 0u;
            lo |= c << (8 * tl);
        }
        int t4 = tgi * 5 + 4;
        unsigned hi = (p >= 1 && ((t4 + 1) % p) == 0) ? 1u : 0u;
        lut8[e] = make_uint2(lo, hi);
    }

    const size_t m5blk = (size_t)blockIdx.x * 32768;   // bytes

    i32x4 acc[8][5];
    #pragma unroll
    for (int n = 0; n < 8; ++n)
        #pragma unroll
        for (int t = 0; t < 5; ++t)
            acc[n][t] = (i32x4){0, 0, 0, 0};

    for (int c = wv; c < 9; c += 4) {
        const char* s = (c < 8) ? ((const char*)W2q + c * 1024)
                                : ((const char*)M5 + m5blk);
        gl_lds16(s + lane * 16, smem + c * 1024);
    }

    const uint2* l8 = lut8 + tg * 704 + lsl;   // + p*32 per lookup

    for (int kt = 0; kt < 32; ++kt) {
        __syncthreads();
        const int cb = (kt & 1) * 9216;
        if (kt < 31) {
            const int nb = ((kt + 1) & 1) * 9216;
            for (int c = wv; c < 9; c += 4) {
                const char* s = (c < 8)
                    ? ((const char*)W2q + (size_t)(kt + 1) * 8192 + c * 1024)
                    : ((const char*)M5 + m5blk + (size_t)(kt + 1) * 1024);
                gl_lds16(s + lane * 16, smem + nb + c * 1024);
            }
        }

        union { uint4 v; unsigned u[4]; } pc;
        pc.v = *reinterpret_cast<const uint4*>(smem + cb + 8192 + lane * 16);

        union { i32x4 v; unsigned u[4]; } A[5];
        #pragma unroll
        for (int g2 = 0; g2 < 4; ++g2) {
            unsigned w = pc.u[g2];
            uint2 q0 = l8[((w      ) & 0xffu) << 5];
            uint2 q1 = l8[((w >>  8) & 0xffu) << 5];
            uint2 q2 = l8[((w >> 16) & 0xffu) << 5];
            uint2 q3 = l8[( w >> 24         ) << 5];
            unsigned u01 = __builtin_amdgcn_perm(q2.x, q0.x, 0x05010400u);
            unsigned u23 = __builtin_amdgcn_perm(q3.x, q1.x, 0x05010400u);
            unsigned v01 = __builtin_amdgcn_perm(q2.x, q0.x, 0x07030602u);
            unsigned v23 = __builtin_amdgcn_perm(q3.x, q1.x, 0x07030602u);
            A[0].u[g2] = __builtin_amdgcn_perm(u23, u01, 0x05040100u);
            A[1].u[g2] = __builtin_amdgcn_perm(u23, u01, 0x07060302u);
            A[2].u[g2] = __builtin_amdgcn_perm(v23, v01, 0x05040100u);
            A[3].u[g2] = __builtin_amdgcn_perm(v23, v01, 0x07060302u);
            unsigned z01 = __builtin_amdgcn_perm(q2.y, q0.y, 0x0C0C0400u);
            unsigned z23 = __builtin_amdgcn_perm(q3.y, q1.y, 0x0C0C0400u);
            A[4].u[g2] = __builtin_amdgcn_perm(z23, z01, 0x05040100u);
        }

        i32x4 Bv[8];
        #pragma unroll
        for (int nt = 0; nt < 8; ++nt)
            Bv[nt] = *reinterpret_cast<const i32x4*>(smem + cb + nt * 1024 + lane * 16);
        #pragma unroll
        for (int tl = 0; tl < 5; ++tl)
            #pragma unroll
            for (int nt = 0; nt < 8; ++nt)
                acc[nt][tl] = __builtin_amdgcn_mfma_i32_16x16x64_i8(
                    A[tl].v, Bv[nt], acc[nt][tl], 0, 0, 0);
    }

    #pragma unroll
    for (int q = 0; q < 8; ++q) {
        __syncthreads();
        #pragma unroll
        for (int tl = 0; tl < 5; ++tl)
            #pragma unroll
            for (int j = 0; j < 4; ++j)
                sm_f32[((g * 4 + j) * 17 + l15) * 21 + (t0 + tl)] = (float)acc[q][tl][j];
        __syncthreads();
        {
            const int bl  = tid >> 4;     // 0..15
            const int c16 = tid & 15;
            const int c   = q * 16 + c16;
            const float bias = b2[c];
            float u2 = 0.0f; int cnt = 0;
            #pragma unroll
            for (int t = 0; t < T_STEPS; ++t) {
                float X = __fadd_rn(__fmul_rn(sm_f32[(bl * 17 + c16) * 21 + t], 0.0009765625f), bias);
                u2 = __fadd_rn(__fmul_rn(0.9f, u2), X);
                if (u2 >= 1.0f) { cnt++; u2 = 0.0f; }
            }
            out[(size_t)(b0 + bl) * C_SZ + c] = (float)cnt / 20.0f;
        }
    }
}

// ---------------- K3: mean_spikes = total / (B * T) ----------------
__global__ void k_finalize(const unsigned int* __restrict__ spike_count, float* __restrict__ out) {
    out[(size_t)B_SZ * C_SZ] = (float)(*spike_count) / (float)((size_t)B_SZ * T_STEPS);
}

extern "C" void kernel_launch(void* const* d_in, const int* in_sizes, int n_in,
                              void* d_out, int out_size, void* d_ws, size_t ws_size,
                              hipStream_t stream) {
    const float* x  = (const float*)d_in[0];
    const float* W1 = (const float*)d_in[1];
    const float* b1 = (const float*)d_in[2];
    const float* W2 = (const float*)d_in[3];
    const float* b2 = (const float*)d_in[4];
    float* out = (float*)d_out;

    char* ws = (char*)d_ws;
    const size_t m5_b   = (size_t)B_SZ * H_SZ;       // 33.6 MB
    const size_t xfi_b  = (size_t)B_SZ * D_SZ;       // 16.8 MB
    const size_t w1fi_b = (size_t)H_SZ * D_SZ;       //  2.1 MB
    const size_t w2q_b  = (size_t)C_SZ * H_SZ;       //  0.26 MB

    size_t off = 0;
    unsigned char*  M5   = (unsigned char*)(ws + off);  off += m5_b;
    signed char*    xfi  = (signed char*)(ws + off);    off += xfi_b;
    signed char*    w1fi = (signed char*)(ws + off);    off += w1fi_b;
    signed char*    w2q  = (signed char*)(ws + off);    off += w2q_b;
    unsigned int* counter = (unsigned int*)(ws + off);  off += 256;

    hipMemsetAsync(counter, 0, sizeof(unsigned int), stream);

    k_w1fragi8<<<512, 256, 0, stream>>>(W1, w1fi);   // 131072 threads EXACT
    k_w2fragi8<<<64, 256, 0, stream>>>(W2, w2q);     // 16384 threads EXACT
    k_xfragi8<<<4096, 256, 0, stream>>>(x, xfi);     // 1048576 threads EXACT

    k_gemm1_i8<<<2048, 256, 0, stream>>>(xfi, w1fi, b1, M5, counter);

    k_layer2_i8<<<B_SZ / 16, 256, 0, stream>>>(M5, w2q, b2, out);

    k_finalize<<<1, 1, 0, stream>>>(counter, out);
}

// Round 24
// 171.664 us; speedup vs baseline: 1.5505x; 1.0490x over previous
//
#include <hip/hip_runtime.h>

#define B_SZ 16384
#define D_SZ 1024
#define H_SZ 2048
#define C_SZ 128
#define T_STEPS 20

typedef __attribute__((ext_vector_type(4))) float f32x4;
typedef __attribute__((ext_vector_type(4))) int   i32x4;

__device__ __forceinline__ signed char to_i8(float f, float s) {
    float v = rintf(s * f);
    v = v > 127.0f ? 127.0f : (v < -127.0f ? -127.0f : v);
    return (signed char)(int)v;
}

__device__ __forceinline__ void gl_lds16(const void* g, void* l) {
    __builtin_amdgcn_global_load_lds(
        (const __attribute__((address_space(1))) unsigned int*)g,
        (__attribute__((address_space(3))) unsigned int*)l, 16, 0, 0);
}

// ---------------- W1 -> i8 frags: [p(16)][kt(16)][wr(2)][m(4)][lane(64)][16B] --------
__global__ void k_w1fragi8(const float* __restrict__ W1, signed char* __restrict__ w1f) {
    int idx = blockIdx.x * blockDim.x + threadIdx.x;   // 0..131071
    int lane = idx & 63;
    int m    = (idx >> 6) & 3;
    int wr   = (idx >> 8) & 1;
    int kt   = (idx >> 9) & 15;
    int p    = idx >> 13;
    int h = p * 128 + wr * 64 + m * 16 + (lane & 15);
    int k = kt * 64 + (lane >> 4) * 16;
    const float* src = W1 + (size_t)h * D_SZ + k;
    union { signed char b[16]; uint4 u; } q;
    #pragma unroll
    for (int q4 = 0; q4 < 4; ++q4) {
        float4 v = *reinterpret_cast<const float4*>(src + q4 * 4);
        q.b[q4 * 4 + 0] = to_i8(v.x, 1024.0f);
        q.b[q4 * 4 + 1] = to_i8(v.y, 1024.0f);
        q.b[q4 * 4 + 2] = to_i8(v.z, 1024.0f);
        q.b[q4 * 4 + 3] = to_i8(v.w, 1024.0f);
    }
    size_t off = (size_t)p * 131072 + (size_t)kt * 8192 + wr * 4096 + m * 1024 + lane * 16;
    *reinterpret_cast<uint4*>(w1f + off) = q.u;
}

// ---------------- x -> i8 frags: [bp(128)][kt(16)][wc(2)][n(4)][lane(64)][16B] -------
__global__ void k_xfragi8(const float* __restrict__ x, signed char* __restrict__ xf) {
    int idx = blockIdx.x * blockDim.x + threadIdx.x;   // 0..1048575
    int lane = idx & 63;
    int n    = (idx >> 6) & 3;
    int wc   = (idx >> 8) & 1;
    int kt   = (idx >> 9) & 15;
    int bp   = idx >> 13;
    int b = bp * 128 + wc * 64 + n * 16 + (lane & 15);
    int k = kt * 64 + (lane >> 4) * 16;
    const float* src = x + (size_t)b * D_SZ + k;
    union { signed char b[16]; uint4 u; } q;
    #pragma unroll
    for (int q4 = 0; q4 < 4; ++q4) {
        float4 v = *reinterpret_cast<const float4*>(src + q4 * 4);
        q.b[q4 * 4 + 0] = to_i8(v.x, 32.0f);
        q.b[q4 * 4 + 1] = to_i8(v.y, 32.0f);
        q.b[q4 * 4 + 2] = to_i8(v.z, 32.0f);
        q.b[q4 * 4 + 3] = to_i8(v.w, 32.0f);
    }
    size_t off = (size_t)bp * 131072 + (size_t)kt * 8192 + wc * 4096 + n * 1024 + lane * 16;
    *reinterpret_cast<uint4*>(xf + off) = q.u;
}

// ---------------- W2 -> i8 frags: [kt64(32)][nt(8)][lane(64)][16B], k-perm baked -----
__global__ void k_w2fragi8(const float* __restrict__ W2, signed char* __restrict__ w2q) {
    const int perm4[4] = {0, 2, 1, 3};
    int idx = blockIdx.x * blockDim.x + threadIdx.x;   // 0..16383
    int lane = idx & 63;
    int nt   = (idx >> 6) & 7;
    int kt   = idx >> 9;                               // 0..31
    int c = nt * 16 + (lane & 15);
    int hbase = kt * 64 + (lane >> 4) * 16;
    const float* src = W2 + (size_t)c * H_SZ + hbase;
    float f[16];
    #pragma unroll
    for (int q4 = 0; q4 < 4; ++q4) {
        float4 v = *reinterpret_cast<const float4*>(src + q4 * 4);
        f[q4 * 4 + 0] = v.x; f[q4 * 4 + 1] = v.y; f[q4 * 4 + 2] = v.z; f[q4 * 4 + 3] = v.w;
    }
    union { signed char b[16]; uint4 u; } q;
    #pragma unroll
    for (int j = 0; j < 16; ++j) {
        int k = (j & ~3) + perm4[j & 3];
        q.b[j] = to_i8(f[k], 1024.0f);
    }
    *reinterpret_cast<uint4*>(w2q + (size_t)idx * 16) = q.u;
}

// ---------------- K1: LDS-staged i8 GEMM + closed-form LIF, 1-byte p-code masks ------
// (round-23 kernel, unchanged)
__global__ __launch_bounds__(256, 3) void k_gemm1_i8(
    const signed char* __restrict__ xf,
    const signed char* __restrict__ w1f,
    const float* __restrict__ b1,
    unsigned char* __restrict__ M5,
    unsigned int* __restrict__ spike_count)
{
    __shared__ unsigned lutm[22];
    __shared__ int sred[4];
    __shared__ __align__(16) char sbuf[2][16384];   // [buf][A 8KB | B 8KB]
    const int tid  = threadIdx.x;
    if (tid < 22) {
        unsigned m = 0;
        if (tid >= 1 && tid <= 20)
            for (int t = tid - 1; t < T_STEPS; t += tid) m |= 1u << t;
        lutm[tid] = m;
    }

    const int wv   = tid >> 6;
    const int lane = tid & 63;
    const int l15  = lane & 15;
    const int g    = lane >> 4;
    const int wr   = wv >> 1;
    const int wc   = wv & 1;

    const int wg    = blockIdx.x;
    const int xcd   = wg & 7;
    const int local = wg >> 3;
    const int sc    = local >> 4;
    const int sl    = local & 15;
    const int b_panel = xcd * 16 + (sc >> 2) * 4 + (sl >> 2);
    const int h_idx   = (sc & 3) * 4 + (sl & 3);

    const signed char* Asrc = w1f + (size_t)h_idx * 131072;
    const signed char* Bsrc = xf + (size_t)b_panel * 131072;

    #pragma unroll
    for (int c = 0; c < 4; ++c) {
        int o = c * 4096 + wv * 1024;
        const signed char* s = (o < 8192) ? (Asrc + o + lane * 16)
                                          : (Bsrc + (o - 8192) + lane * 16);
        gl_lds16(s, sbuf[0] + o);
    }

    i32x4 acc[4][4];
    #pragma unroll
    for (int i = 0; i < 4; ++i)
        #pragma unroll
        for (int j = 0; j < 4; ++j)
            acc[i][j] = (i32x4){0, 0, 0, 0};

    for (int kt = 0; kt < 16; ++kt) {
        __syncthreads();
        if (kt < 15) {
            #pragma unroll
            for (int c = 0; c < 4; ++c) {
                int o = c * 4096 + wv * 1024;
                const signed char* s = (o < 8192)
                    ? (Asrc + (size_t)(kt + 1) * 8192 + o + lane * 16)
                    : (Bsrc + (size_t)(kt + 1) * 8192 + (o - 8192) + lane * 16);
                gl_lds16(s, sbuf[(kt + 1) & 1] + o);
            }
        }
        const char* base = sbuf[kt & 1];
        i32x4 A[4], Bv[4];
        #pragma unroll
        for (int m = 0; m < 4; ++m)
            A[m] = *reinterpret_cast<const i32x4*>(base + wr * 4096 + m * 1024 + lane * 16);
        #pragma unroll
        for (int n = 0; n < 4; ++n)
            Bv[n] = *reinterpret_cast<const i32x4*>(base + 8192 + wc * 4096 + n * 1024 + lane * 16);
        #pragma unroll
        for (int m = 0; m < 4; ++m)
            #pragma unroll
            for (int n = 0; n < 4; ++n)
                acc[m][n] = __builtin_amdgcn_mfma_i32_16x16x64_i8(
                    A[m], Bv[n], acc[m][n], 0, 0, 0);
    }

    int spikes = 0;
    #pragma unroll
    for (int m = 0; m < 4; ++m) {
        const int h0l = h_idx * 128 + wr * 64 + m * 16 + g * 4;
        const int kt64 = h_idx * 2 + wr;
        const int k2lane = m * 16 + l15;
        float4 bias = *reinterpret_cast<const float4*>(b1 + h0l);
        float bj[4] = {bias.x, bias.y, bias.z, bias.w};
        #pragma unroll
        for (int n = 0; n < 4; ++n) {
            const int bt = b_panel * 8 + wc * 4 + n;
            unsigned pcode = 0;
            #pragma unroll
            for (int j = 0; j < 4; ++j) {
                float i1 = __fmul_rn((float)acc[m][n][j], 3.0517578125e-05f) + bj[j];
                float arg = fmaf(-0.1f, __builtin_amdgcn_rcpf(i1), 1.0f);
                float pf = ceilf(__log2f(arg) * -6.578813478960192f);
                int p = (int)pf;
                p = p < 1 ? 1 : (p > 21 ? 21 : p);
                int pe = (i1 >= 0.113843485f) ? p : 0;
                spikes += __popc(lutm[pe]);
                pcode |= (unsigned)pe << (8 * j);
            }
            const size_t rec = ((size_t)bt * 32 + kt64) * 64 + k2lane;
            *reinterpret_cast<unsigned int*>(M5 + rec * 16 + g * 4) = pcode;
        }
    }
    #pragma unroll
    for (int off = 32; off > 0; off >>= 1)
        spikes += __shfl_down(spikes, off);
    if (lane == 0) sred[wv] = spikes;
    __syncthreads();
    if (tid == 0)
        atomicAdd(spike_count, (unsigned int)(sred[0] + sred[1] + sred[2] + sred[3]));
}

// ---------------- K2: layer 2 i8 K=64; ALL pcodes pre-staged + fused b64 LUT ---------
// Block's pcode slice (32KB) staged once in prologue -> per-kt staging is w2-only
// (2 static gl_lds16/wave, no dynamic chunk loop), and pc[kt] is valid from the
// first barrier so the pc->lut->perm chain starts at iter top. Bit-exact vs r22.
__global__ __launch_bounds__(256, 2) void k_layer2_i8(
    const unsigned char* __restrict__ M5,
    const signed char* __restrict__ W2q,
    const float* __restrict__ b2,
    float* __restrict__ out)
{
    __shared__ __align__(16) char smem[71680];   // [0,16K) w2 dbuf; [16K,48K) pcodes; [48K,70K) lut8
    float* sm_f32 = (float*)smem;
    uint2* lut8 = (uint2*)(smem + 49152);        // [tg(4)][p(22)][repl(32)] uint2

    const int tid  = threadIdx.x;
    const int wv   = tid >> 6;        // 0..3
    const int tg   = wv;              // t in [tg*5, tg*5+5)
    const int lane = tid & 63;
    const int l15  = lane & 15;
    const int g    = lane >> 4;
    const int b0   = blockIdx.x * 16;
    const int t0   = tg * 5;
    const int lsl  = lane & 31;

    for (int e = tid; e < 2816; e += 256) {
        int tgi = e / 704;
        int p   = (e - tgi * 704) >> 5;
        unsigned lo = 0;
        #pragma unroll
        for (int tl = 0; tl < 4; ++tl) {
            int t = tgi * 5 + tl;
            unsigned c = (p >= 1 && ((t + 1) % p) == 0) ? 1u : 0u;
            lo |= c << (8 * tl);
        }
        int t4 = tgi * 5 + 4;
        unsigned hi = (p >= 1 && ((t4 + 1) % p) == 0) ? 1u : 0u;
        lut8[e] = make_uint2(lo, hi);
    }

    const size_t m5blk = (size_t)blockIdx.x * 32768;   // bytes

    i32x4 acc[8][5];
    #pragma unroll
    for (int n = 0; n < 8; ++n)
        #pragma unroll
        for (int t = 0; t < 5; ++t)
            acc[n][t] = (i32x4){0, 0, 0, 0};

    // prologue: stage w2[0] (chunks 0..7) + ALL pcodes (chunks 8..39)
    for (int c = wv; c < 40; c += 4) {
        if (c < 8)
            gl_lds16((const char*)W2q + c * 1024 + lane * 16, smem + c * 1024);
        else
            gl_lds16((const char*)M5 + m5blk + (size_t)(c - 8) * 1024 + lane * 16,
                     smem + 16384 + (c - 8) * 1024);
    }

    const uint2* l8 = lut8 + tg * 704 + lsl;   // + p*32 per lookup

    for (int kt = 0; kt < 32; ++kt) {
        __syncthreads();
        const int cb = (kt & 1) * 8192;
        if (kt < 31) {
            const int nb = ((kt + 1) & 1) * 8192;
            gl_lds16((const char*)W2q + (size_t)(kt + 1) * 8192 + wv * 1024 + lane * 16,
                     smem + nb + wv * 1024);
            gl_lds16((const char*)W2q + (size_t)(kt + 1) * 8192 + (wv + 4) * 1024 + lane * 16,
                     smem + nb + (wv + 4) * 1024);
        }

        union { uint4 v; unsigned u[4]; } pc;
        pc.v = *reinterpret_cast<const uint4*>(smem + 16384 + kt * 1024 + lane * 16);

        union { i32x4 v; unsigned u[4]; } A[5];
        #pragma unroll
        for (int g2 = 0; g2 < 4; ++g2) {
            unsigned w = pc.u[g2];
            uint2 q0 = l8[((w      ) & 0xffu) << 5];
            uint2 q1 = l8[((w >>  8) & 0xffu) << 5];
            uint2 q2 = l8[((w >> 16) & 0xffu) << 5];
            uint2 q3 = l8[( w >> 24         ) << 5];
            unsigned u01 = __builtin_amdgcn_perm(q2.x, q0.x, 0x05010400u);
            unsigned u23 = __builtin_amdgcn_perm(q3.x, q1.x, 0x05010400u);
            unsigned v01 = __builtin_amdgcn_perm(q2.x, q0.x, 0x07030602u);
            unsigned v23 = __builtin_amdgcn_perm(q3.x, q1.x, 0x07030602u);
            A[0].u[g2] = __builtin_amdgcn_perm(u23, u01, 0x05040100u);
            A[1].u[g2] = __builtin_amdgcn_perm(u23, u01, 0x07060302u);
            A[2].u[g2] = __builtin_amdgcn_perm(v23, v01, 0x05040100u);
            A[3].u[g2] = __builtin_amdgcn_perm(v23, v01, 0x07060302u);
            unsigned z01 = __builtin_amdgcn_perm(q2.y, q0.y, 0x0C0C0400u);
            unsigned z23 = __builtin_amdgcn_perm(q3.y, q1.y, 0x0C0C0400u);
            A[4].u[g2] = __builtin_amdgcn_perm(z23, z01, 0x05040100u);
        }

        i32x4 Bv[8];
        #pragma unroll
        for (int nt = 0; nt < 8; ++nt)
            Bv[nt] = *reinterpret_cast<const i32x4*>(smem + cb + nt * 1024 + lane * 16);
        #pragma unroll
        for (int tl = 0; tl < 5; ++tl)
            #pragma unroll
            for (int nt = 0; nt < 8; ++nt)
                acc[nt][tl] = __builtin_amdgcn_mfma_i32_16x16x64_i8(
                    A[tl].v, Bv[nt], acc[nt][tl], 0, 0, 0);
    }

    // epilogue: 8 chunks of 16 cols; transpose through LDS, then LIF per (b,c)
    #pragma unroll
    for (int q = 0; q < 8; ++q) {
        __syncthreads();
        #pragma unroll
        for (int tl = 0; tl < 5; ++tl)
            #pragma unroll
            for (int j = 0; j < 4; ++j)
                sm_f32[((g * 4 + j) * 17 + l15) * 21 + (t0 + tl)] = (float)acc[q][tl][j];
        __syncthreads();
        {
            const int bl  = tid >> 4;     // 0..15
            const int c16 = tid & 15;
            const int c   = q * 16 + c16;
            const float bias = b2[c];
            float u2 = 0.0f; int cnt = 0;
            #pragma unroll
            for (int t = 0; t < T_STEPS; ++t) {
                float X = __fadd_rn(__fmul_rn(sm_f32[(bl * 17 + c16) * 21 + t], 0.0009765625f), bias);
                u2 = __fadd_rn(__fmul_rn(0.9f, u2), X);
                if (u2 >= 1.0f) { cnt++; u2 = 0.0f; }
            }
            out[(size_t)(b0 + bl) * C_SZ + c] = (float)cnt / 20.0f;
        }
    }
}

// ---------------- K3: mean_spikes = total / (B * T) ----------------
__global__ void k_finalize(const unsigned int* __restrict__ spike_count, float* __restrict__ out) {
    out[(size_t)B_SZ * C_SZ] = (float)(*spike_count) / (float)((size_t)B_SZ * T_STEPS);
}

extern "C" void kernel_launch(void* const* d_in, const int* in_sizes, int n_in,
                              void* d_out, int out_size, void* d_ws, size_t ws_size,
                              hipStream_t stream) {
    const float* x  = (const float*)d_in[0];
    const float* W1 = (const float*)d_in[1];
    const float* b1 = (const float*)d_in[2];
    const float* W2 = (const float*)d_in[3];
    const float* b2 = (const float*)d_in[4];
    float* out = (float*)d_out;

    char* ws = (char*)d_ws;
    const size_t m5_b   = (size_t)B_SZ * H_SZ;       // 33.6 MB
    const size_t xfi_b  = (size_t)B_SZ * D_SZ;       // 16.8 MB
    const size_t w1fi_b = (size_t)H_SZ * D_SZ;       //  2.1 MB
    const size_t w2q_b  = (size_t)C_SZ * H_SZ;       //  0.26 MB

    size_t off = 0;
    unsigned char*  M5   = (unsigned char*)(ws + off);  off += m5_b;
    signed char*    xfi  = (signed char*)(ws + off);    off += xfi_b;
    signed char*    w1fi = (signed char*)(ws + off);    off += w1fi_b;
    signed char*    w2q  = (signed char*)(ws + off);    off += w2q_b;
    unsigned int* counter = (unsigned int*)(ws + off);  off += 256;

    hipMemsetAsync(counter, 0, sizeof(unsigned int), stream);

    k_w1fragi8<<<512, 256, 0, stream>>>(W1, w1fi);   // 131072 threads EXACT
    k_w2fragi8<<<64, 256, 0, stream>>>(W2, w2q);     // 16384 threads EXACT
    k_xfragi8<<<4096, 256, 0, stream>>>(x, xfi);     // 1048576 threads EXACT

    k_gemm1_i8<<<2048, 256, 0, stream>>>(xfi, w1fi, b1, M5, counter);

    k_layer2_i8<<<B_SZ / 16, 256, 0, stream>>>(M5, w2q, b2, out);

    k_finalize<<<1, 1, 0, stream>>>(counter, out);
}